// Round 9
// baseline (1152.389 us; speedup 1.0000x reference)
//
#include <hip/hip_runtime.h>
#include <hip/hip_bf16.h>
#include <math.h>

#define USER_NUM 100000
#define ITEM_NUM 50000
#define N_NODES  150000
#define N_EDGES  2400000
#define OUT_DIM  64
#define HID_DIM  128
#define BATCH    4096
#define EPS_BN   1e-5f

typedef unsigned short ushort_t;
typedef unsigned int uint_t;

// fp32 -> bf16 (round-to-nearest-even), and back
__device__ __forceinline__ ushort_t f2bf(float f) {
    uint_t u = __float_as_uint(f);
    u += 0x7FFFu + ((u >> 16) & 1u);
    return (ushort_t)(u >> 16);
}
__device__ __forceinline__ float bf2f(ushort_t s) {
    return __uint_as_float((uint_t)s << 16);
}

// ---------------- preprocessing ----------------

__global__ __launch_bounds__(256) void zero_int_kernel(int* __restrict__ p, int n) {
    int i = blockIdx.x * 256 + threadIdx.x;
    if (i < n) p[i] = 0;
}

__global__ __launch_bounds__(256) void count_kernel(const int* __restrict__ dst, int* __restrict__ cnt) {
    int i = blockIdx.x * 256 + threadIdx.x;
    if (i < N_EDGES) atomicAdd(&cnt[dst[i]], 1);
}

__global__ __launch_bounds__(256) void dis_kernel(const int* __restrict__ cnt, float* __restrict__ dis) {
    int i = blockIdx.x * 256 + threadIdx.x;
    if (i < N_NODES) dis[i] = rsqrtf(1.0f + (float)cnt[i]);
}

// 3-pass scan: per-block sums -> scan of block sums -> emit offsets
#define SC_ELEM 1024
#define SC_NB   ((N_NODES + SC_ELEM - 1) / SC_ELEM)   // 147

__global__ __launch_bounds__(256) void scan_part_kernel(const int* __restrict__ cnt,
                                                        int* __restrict__ psum) {
    __shared__ int red[4];
    int tid = threadIdx.x;
    int base = blockIdx.x * SC_ELEM + tid * 4;
    int s = 0;
#pragma unroll
    for (int j = 0; j < 4; j++) { int i = base + j; if (i < N_NODES) s += cnt[i]; }
#pragma unroll
    for (int d = 1; d < 64; d <<= 1) s += __shfl_xor(s, d);
    if ((tid & 63) == 0) red[tid >> 6] = s;
    __syncthreads();
    if (tid == 0) psum[blockIdx.x] = red[0] + red[1] + red[2] + red[3];
}

__global__ __launch_bounds__(256) void scan_mid_kernel(int* __restrict__ psum,
                                                       int* __restrict__ off, int nb) {
    __shared__ int lds[256];
    int tid = threadIdx.x;
    int v = (tid < nb) ? psum[tid] : 0;
    lds[tid] = v;
    __syncthreads();
    for (int d = 1; d < 256; d <<= 1) {
        int t = (tid >= d) ? lds[tid - d] : 0;
        __syncthreads();
        lds[tid] += t;
        __syncthreads();
    }
    if (tid < nb) psum[tid] = lds[tid] - v;   // exclusive
    if (tid == 0) off[N_NODES] = lds[255];
}

__global__ __launch_bounds__(256) void scan_emit_kernel(const int* __restrict__ cnt,
                                                        const int* __restrict__ psum,
                                                        int* __restrict__ off,
                                                        int* __restrict__ cur) {
    __shared__ int lds[256];
    int tid = threadIdx.x;
    int base = blockIdx.x * SC_ELEM + tid * 4;
    int v[4]; int s = 0;
#pragma unroll
    for (int j = 0; j < 4; j++) {
        int i = base + j;
        v[j] = (i < N_NODES) ? cnt[i] : 0;
        s += v[j];
    }
    lds[tid] = s;
    __syncthreads();
    for (int d = 1; d < 256; d <<= 1) {
        int t = (tid >= d) ? lds[tid - d] : 0;
        __syncthreads();
        lds[tid] += t;
        __syncthreads();
    }
    int run = psum[blockIdx.x] + lds[tid] - s;
#pragma unroll
    for (int j = 0; j < 4; j++) {
        int i = base + j;
        if (i < N_NODES) { off[i] = run; cur[i] = run; }
        run += v[j];
    }
}

// XCD-parity-partitioned CSR fill.
// Line-owner class of a csr8 line = (dst>>3)&7 (8-node groups). Block bid
// handles edge chunk bid>>3 and only edges of class bid&7; with round-robin
// workgroup->XCD dispatch each csr8 line is written by ONE XCD, so lines
// fill completely in that L2 before eviction (kills the 8x write blowup).
// Correctness does not depend on the XCD mapping.
#define FILL_BLOCKS 2048
#define FILL_CHUNKS (FILL_BLOCKS / 8)     // 256

__global__ __launch_bounds__(256) void fill_kernel(const int* __restrict__ src, const int* __restrict__ dst,
                                                   const float* __restrict__ dis,
                                                   int* __restrict__ cursor,
                                                   uint2* __restrict__ csr8) {
    const int parity = blockIdx.x & 7;
    const int chunk  = blockIdx.x >> 3;
    const int per    = (N_EDGES + FILL_CHUNKS - 1) / FILL_CHUNKS;   // 9375
    int lo = chunk * per;
    int hi = lo + per; if (hi > N_EDGES) hi = N_EDGES;
    for (int i = lo + threadIdx.x; i < hi; i += 256) {
        int d = dst[i];
        if (((d >> 3) & 7) != parity) continue;
        int s = src[i];
        int p = atomicAdd(&cursor[d], 1);
        uint2 e;
        e.x = (uint_t)s;
        e.y = __float_as_uint(dis[s] * dis[d]);
        csr8[p] = e;
    }
}

// ---------------- GEMM: out[M][DOUT] = x[M][DIN] @ W[DIN][DOUT], bf16 output ----------------
// XT = float or ushort_t (bf16) input. 256 threads, block tile MBLK x DOUT,
// micro-tile 8x8 per thread, K-chunks of 32 in LDS with reg-staged prefetch.

__device__ __forceinline__ float4 load4(const float* p) { return *(const float4*)p; }
__device__ __forceinline__ float4 load4(const ushort_t* p) {
    ushort4 u = *(const ushort4*)p;
    return make_float4(bf2f(u.x), bf2f(u.y), bf2f(u.z), bf2f(u.w));
}

template<typename XT, int DIN, int DOUT, int MBLK>
__global__ __launch_bounds__(256) void gemm_kernel(const XT* __restrict__ xlo,
                                                   const XT* __restrict__ xhi, int split,
                                                   const float* __restrict__ W,
                                                   ushort_t* __restrict__ out, int nrows) {
    constexpr int KC    = 32;
    constexpr int NC    = DIN / KC;
    constexpr int XS_PT = MBLK / 32;      // 4-elem x-loads per thread per chunk
    constexpr int WS_PT = DOUT / 32;      // float4 w-loads per thread per chunk
    constexpr int NCOLG = DOUT / 8;

    __shared__ float xs[MBLK][KC + 1];    // +1 pad: conflict-free column reads
    __shared__ float ws[KC][DOUT];

    const int tid  = threadIdx.x;
    const int row0 = blockIdx.x * MBLK;
    const int colg = tid % NCOLG;
    const int rowg = tid / NCOLG;

    float4 xr[XS_PT], wr[WS_PT];

    auto load_chunk = [&](int kc) {
#pragma unroll
        for (int i = 0; i < XS_PT; i++) {
            int idx = i * 256 + tid;
            int m = idx >> 3, kq = idx & 7;
            int row = row0 + m; if (row > nrows - 1) row = nrows - 1;
            const XT* rp = (row < split) ? xlo + (size_t)row * DIN
                                         : xhi + (size_t)(row - split) * DIN;
            xr[i] = load4(rp + kc + kq * 4);
        }
#pragma unroll
        for (int i = 0; i < WS_PT; i++) {
            int idx = i * 256 + tid;
            int n4 = idx % (DOUT / 4), kk = idx / (DOUT / 4);
            wr[i] = *(const float4*)(W + (size_t)(kc + kk) * DOUT + n4 * 4);
        }
    };
    auto write_chunk = [&]() {
#pragma unroll
        for (int i = 0; i < XS_PT; i++) {
            int idx = i * 256 + tid;
            int m = idx >> 3, kq = idx & 7;
            xs[m][kq * 4 + 0] = xr[i].x;
            xs[m][kq * 4 + 1] = xr[i].y;
            xs[m][kq * 4 + 2] = xr[i].z;
            xs[m][kq * 4 + 3] = xr[i].w;
        }
#pragma unroll
        for (int i = 0; i < WS_PT; i++) {
            int idx = i * 256 + tid;
            int n4 = idx % (DOUT / 4), kk = idx / (DOUT / 4);
            *(float4*)&ws[kk][n4 * 4] = wr[i];
        }
    };

    float acc[8][8];
#pragma unroll
    for (int r = 0; r < 8; r++)
#pragma unroll
        for (int c = 0; c < 8; c++) acc[r][c] = 0.f;

    load_chunk(0);
    write_chunk();
    __syncthreads();

    for (int c = 0; c < NC; c++) {
        if (c + 1 < NC) load_chunk((c + 1) * KC);   // prefetch under compute
#pragma unroll 4
        for (int k = 0; k < KC; k++) {
            float4 wa = *(const float4*)&ws[k][colg * 8];
            float4 wb = *(const float4*)&ws[k][colg * 8 + 4];
            float xv[8];
#pragma unroll
            for (int r = 0; r < 8; r++) xv[r] = xs[rowg * 8 + r][k];
#pragma unroll
            for (int r = 0; r < 8; r++) {
                acc[r][0] = fmaf(xv[r], wa.x, acc[r][0]);
                acc[r][1] = fmaf(xv[r], wa.y, acc[r][1]);
                acc[r][2] = fmaf(xv[r], wa.z, acc[r][2]);
                acc[r][3] = fmaf(xv[r], wa.w, acc[r][3]);
                acc[r][4] = fmaf(xv[r], wb.x, acc[r][4]);
                acc[r][5] = fmaf(xv[r], wb.y, acc[r][5]);
                acc[r][6] = fmaf(xv[r], wb.z, acc[r][6]);
                acc[r][7] = fmaf(xv[r], wb.w, acc[r][7]);
            }
        }
        __syncthreads();
        if (c + 1 < NC) { write_chunk(); __syncthreads(); }
    }

#pragma unroll
    for (int r = 0; r < 8; r++) {
        int row = row0 + rowg * 8 + r;
        if (row < nrows) {
            uint4 pk;
            pk.x = (uint_t)f2bf(acc[r][0]) | ((uint_t)f2bf(acc[r][1]) << 16);
            pk.y = (uint_t)f2bf(acc[r][2]) | ((uint_t)f2bf(acc[r][3]) << 16);
            pk.z = (uint_t)f2bf(acc[r][4]) | ((uint_t)f2bf(acc[r][5]) << 16);
            pk.w = (uint_t)f2bf(acc[r][6]) | ((uint_t)f2bf(acc[r][7]) << 16);
            *(uint4*)&out[(size_t)row * DOUT + colg * 8] = pk;
        }
    }
}

// ---------------- edge aggregation (CSR gather over bf16 h, one wave per node) ----------------
// out[i] = sum_e w_e*h[s_e] + h[i]*dis[i]^2 + bias   (fp32 accumulate/output)

template<int DOUT>
__global__ __launch_bounds__(256) void agg_kernel(const ushort_t* __restrict__ h,
                                                  const float* __restrict__ dis,
                                                  const int* __restrict__ off,
                                                  const uint2* __restrict__ csr8,
                                                  const float* __restrict__ bias,
                                                  float* __restrict__ out, int n) {
    int wave = threadIdx.x >> 6;
    int lane = threadIdx.x & 63;
    int node = blockIdx.x * 4 + wave;
    if (node >= n) return;
    float di  = dis[node];
    int   beg = off[node], end = off[node + 1];
    if (DOUT == 128) {
        const uint_t* hp = (const uint_t*)h;   // 64 uints (128 bf16) per row
        float ax = 0.f, ay = 0.f;
        int e = beg;
        for (; e + 4 <= end; e += 4) {
            uint2 e0 = csr8[e], e1 = csr8[e + 1], e2 = csr8[e + 2], e3 = csr8[e + 3];
            uint_t u0 = hp[(size_t)e0.x * 64 + lane];
            uint_t u1 = hp[(size_t)e1.x * 64 + lane];
            uint_t u2 = hp[(size_t)e2.x * 64 + lane];
            uint_t u3 = hp[(size_t)e3.x * 64 + lane];
            float w0 = __uint_as_float(e0.y), w1 = __uint_as_float(e1.y);
            float w2 = __uint_as_float(e2.y), w3 = __uint_as_float(e3.y);
            ax = fmaf(__uint_as_float(u0 << 16), w0, ax);
            ay = fmaf(__uint_as_float(u0 & 0xFFFF0000u), w0, ay);
            ax = fmaf(__uint_as_float(u1 << 16), w1, ax);
            ay = fmaf(__uint_as_float(u1 & 0xFFFF0000u), w1, ay);
            ax = fmaf(__uint_as_float(u2 << 16), w2, ax);
            ay = fmaf(__uint_as_float(u2 & 0xFFFF0000u), w2, ay);
            ax = fmaf(__uint_as_float(u3 << 16), w3, ax);
            ay = fmaf(__uint_as_float(u3 & 0xFFFF0000u), w3, ay);
        }
        for (; e < end; e++) {
            uint2 ev = csr8[e];
            float wv = __uint_as_float(ev.y);
            uint_t u = hp[(size_t)ev.x * 64 + lane];
            ax = fmaf(__uint_as_float(u << 16), wv, ax);
            ay = fmaf(__uint_as_float(u & 0xFFFF0000u), wv, ay);
        }
        uint_t us = hp[(size_t)node * 64 + lane];
        float2 bb = ((const float2*)bias)[lane];
        float dd = di * di;
        float2 o;
        o.x = ax + __uint_as_float(us << 16) * dd + bb.x;
        o.y = ay + __uint_as_float(us & 0xFFFF0000u) * dd + bb.y;
        ((float2*)out)[(size_t)node * 64 + lane] = o;
    } else {
        float ax = 0.f;
        int e = beg;
        for (; e + 4 <= end; e += 4) {
            uint2 e0 = csr8[e], e1 = csr8[e + 1], e2 = csr8[e + 2], e3 = csr8[e + 3];
            float h0 = bf2f(h[(size_t)e0.x * 64 + lane]);
            float h1 = bf2f(h[(size_t)e1.x * 64 + lane]);
            float h2 = bf2f(h[(size_t)e2.x * 64 + lane]);
            float h3 = bf2f(h[(size_t)e3.x * 64 + lane]);
            ax = fmaf(h0, __uint_as_float(e0.y), ax);
            ax = fmaf(h1, __uint_as_float(e1.y), ax);
            ax = fmaf(h2, __uint_as_float(e2.y), ax);
            ax = fmaf(h3, __uint_as_float(e3.y), ax);
        }
        for (; e < end; e++) {
            uint2 ev = csr8[e];
            ax = fmaf(bf2f(h[(size_t)ev.x * 64 + lane]), __uint_as_float(ev.y), ax);
        }
        float hs = bf2f(h[(size_t)node * 64 + lane]);
        out[(size_t)node * 64 + lane] = ax + hs * di * di + bias[lane];
    }
}

// ---------------- BN stats (two-stage, double partials) ----------------

#define STATS_NB 512

__global__ __launch_bounds__(128) void stats1_kernel(const float* __restrict__ x,
                                                     double* __restrict__ part) {
    int col = threadIdx.x;
    double a = 0.0, b = 0.0;
    for (int row = blockIdx.x; row < N_NODES; row += STATS_NB) {
        float v = x[(size_t)row * HID_DIM + col];
        a += v;
        b += (double)v * (double)v;
    }
    part[(size_t)blockIdx.x * 256 + col]       = a;
    part[(size_t)blockIdx.x * 256 + 128 + col] = b;
}

// parallel final reduce: one block per column, 256 threads sweep the partials
__global__ __launch_bounds__(256) void stats2_kernel(const double* __restrict__ part,
                                                     const float* __restrict__ g,
                                                     const float* __restrict__ beta,
                                                     float* __restrict__ a_out,
                                                     float* __restrict__ b_out) {
    __shared__ double red1[4], red2[4];
    int col = blockIdx.x;       // 0..127
    int tid = threadIdx.x;
    double s1 = 0.0, s2 = 0.0;
    for (int p = tid; p < STATS_NB; p += 256) {
        s1 += part[(size_t)p * 256 + col];
        s2 += part[(size_t)p * 256 + 128 + col];
    }
#pragma unroll
    for (int d = 32; d >= 1; d >>= 1) {
        s1 += __shfl_xor(s1, d);
        s2 += __shfl_xor(s2, d);
    }
    int wave = tid >> 6, lane = tid & 63;
    if (lane == 0) { red1[wave] = s1; red2[wave] = s2; }
    __syncthreads();
    if (tid == 0) {
        double t1 = red1[0] + red1[1] + red1[2] + red1[3];
        double t2 = red2[0] + red2[1] + red2[2] + red2[3];
        double mean = t1 / (double)N_NODES;
        double var  = t2 / (double)N_NODES - mean * mean;
        float inv = rsqrtf((float)var + EPS_BN);
        float aa  = g[col] * inv;
        a_out[col] = aa;
        b_out[col] = beta[col] - (float)mean * aa;
    }
}

// ---------------- fused BN-apply + ReLU + row L2-norm -> bf16 (wave per row) ----------------

__global__ __launch_bounds__(256) void bn_relu_l2_kernel(const float* __restrict__ in,
                                                         const float* __restrict__ a,
                                                         const float* __restrict__ b,
                                                         uint_t* __restrict__ outp, int n) {
    int wave = threadIdx.x >> 6;
    int lane = threadIdx.x & 63;
    int row  = blockIdx.x * 4 + wave;
    if (row >= n) return;
    float2 v  = *(const float2*)(in + (size_t)row * 128 + lane * 2);
    float2 aa = *(const float2*)(a + lane * 2);
    float2 bb = *(const float2*)(b + lane * 2);
    float y0 = fmaxf(fmaf(v.x, aa.x, bb.x), 0.f);
    float y1 = fmaxf(fmaf(v.y, aa.y, bb.y), 0.f);
    float ss = y0 * y0 + y1 * y1;
#pragma unroll
    for (int d = 32; d >= 1; d >>= 1) ss += __shfl_xor(ss, d);
    float nn  = sqrtf(ss);
    float inv = 1.f / fmaxf(nn, 1e-12f);
    uint_t pk = (uint_t)f2bf(y0 * inv) | ((uint_t)f2bf(y1 * inv) << 16);
    outp[(size_t)row * 64 + lane] = pk;
}

// ---------------- loss ----------------

__global__ void zero_float_kernel(float* p) { *p = 0.f; }

__global__ __launch_bounds__(256) void loss_kernel(const float* __restrict__ X,
                                                   const int* __restrict__ uid,
                                                   const int* __restrict__ pid,
                                                   const int* __restrict__ nid,
                                                   float* __restrict__ out0) {
    int wave = threadIdx.x >> 6;
    int lane = threadIdx.x & 63;
    int b = blockIdx.x * 4 + wave;
    if (b >= BATCH) return;
    const float* u = X + (size_t)uid[b] * OUT_DIM;
    const float* p = X + (size_t)(USER_NUM + pid[b]) * OUT_DIM;
    const float* q = X + (size_t)(USER_NUM + nid[b]) * OUT_DIM;
    float uv = u[lane];
    float ps = uv * p[lane];
    float ns = uv * q[lane];
#pragma unroll
    for (int d = 32; d >= 1; d >>= 1) {
        ps += __shfl_xor(ps, d);
        ns += __shfl_xor(ns, d);
    }
    if (lane == 0) {
        float t  = ns - ps;                                   // -(pos - neg)
        float sp = fmaxf(t, 0.f) + log1pf(expf(-fabsf(t)));   // softplus(t)
        atomicAdd(out0, sp * (1.0f / BATCH));
    }
}

// ---------------- launch ----------------

extern "C" void kernel_launch(void* const* d_in, const int* in_sizes, int n_in,
                              void* d_out, int out_size, void* d_ws, size_t ws_size,
                              hipStream_t stream) {
    const float* user_emb = (const float*)d_in[0];
    const float* item_emb = (const float*)d_in[1];
    const float* W0  = (const float*)d_in[2];
    const float* b0  = (const float*)d_in[3];
    const float* g0  = (const float*)d_in[4];
    const float* be0 = (const float*)d_in[5];
    const float* W1  = (const float*)d_in[6];
    const float* b1  = (const float*)d_in[7];
    const float* g1  = (const float*)d_in[8];
    const float* be1 = (const float*)d_in[9];
    const float* W2  = (const float*)d_in[10];
    const float* b2  = (const float*)d_in[11];
    const int* user_id  = (const int*)d_in[12];
    const int* pos_item = (const int*)d_in[13];
    const int* neg_item = (const int*)d_in[14];
    const int* edge     = (const int*)d_in[15];
    const int* src = edge;
    const int* dst = edge + N_EDGES;

    char* w = (char*)d_ws;
    auto alloc = [&](size_t bytes) -> char* {
        char* r = w;
        w += (bytes + 255) / 256 * 256;
        return r;
    };
    int*      cnt  = (int*)alloc((size_t)N_NODES * 4);
    int*      off  = (int*)alloc((size_t)(N_NODES + 1) * 4);
    int*      cur  = (int*)alloc((size_t)N_NODES * 4);
    uint2*    csr8 = (uint2*)alloc((size_t)N_EDGES * 8);
    float*    dis  = (float*)alloc((size_t)N_NODES * 4);
    int*      psum = (int*)alloc((size_t)SC_NB * 4);
    double*   part = (double*)alloc((size_t)STATS_NB * 256 * 8);
    float*    bn_a = (float*)alloc(128 * 4);
    float*    bn_b = (float*)alloc(128 * 4);
    ushort_t* hbuf = (ushort_t*)alloc((size_t)N_NODES * HID_DIM * 2);   // bf16 GEMM output
    float*    xbuf = (float*)alloc((size_t)N_NODES * HID_DIM * 4);      // fp32 agg output
    ushort_t* xbf  = (ushort_t*)alloc((size_t)N_NODES * HID_DIM * 2);   // bf16 normalized x

    float* out = (float*)d_out;
    float* X   = out + 1;   // node embeddings region (150000 x 64)

    const int EB = (N_EDGES + 255) / 256;
    const int NB = (N_NODES + 255) / 256;
    const int AGGB = (N_NODES + 3) / 4;

    // preprocessing: degree, dis, CSR (+ fused per-edge weights)
    zero_int_kernel<<<NB, 256, 0, stream>>>(cnt, N_NODES);
    count_kernel<<<EB, 256, 0, stream>>>(dst, cnt);
    dis_kernel<<<NB, 256, 0, stream>>>(cnt, dis);
    scan_part_kernel<<<SC_NB, 256, 0, stream>>>(cnt, psum);
    scan_mid_kernel<<<1, 256, 0, stream>>>(psum, off, SC_NB);
    scan_emit_kernel<<<SC_NB, 256, 0, stream>>>(cnt, psum, off, cur);
    fill_kernel<<<FILL_BLOCKS, 256, 0, stream>>>(src, dst, dis, cur, csr8);

    // layer 0: (150000x64 fp32) @ (64x128)
    gemm_kernel<float, 64, 128, 128><<<(N_NODES + 127) / 128, 256, 0, stream>>>(
        user_emb, item_emb, USER_NUM, W0, hbuf, N_NODES);
    agg_kernel<128><<<AGGB, 256, 0, stream>>>(hbuf, dis, off, csr8, b0, xbuf, N_NODES);
    stats1_kernel<<<STATS_NB, 128, 0, stream>>>(xbuf, part);
    stats2_kernel<<<128, 256, 0, stream>>>(part, g0, be0, bn_a, bn_b);
    bn_relu_l2_kernel<<<AGGB, 256, 0, stream>>>(xbuf, bn_a, bn_b, (uint_t*)xbf, N_NODES);

    // layer 1: (150000x128 bf16) @ (128x128)
    gemm_kernel<ushort_t, 128, 128, 128><<<(N_NODES + 127) / 128, 256, 0, stream>>>(
        xbf, xbf, N_NODES, W1, hbuf, N_NODES);
    agg_kernel<128><<<AGGB, 256, 0, stream>>>(hbuf, dis, off, csr8, b1, xbuf, N_NODES);
    stats1_kernel<<<STATS_NB, 128, 0, stream>>>(xbuf, part);
    stats2_kernel<<<128, 256, 0, stream>>>(part, g1, be1, bn_a, bn_b);
    bn_relu_l2_kernel<<<AGGB, 256, 0, stream>>>(xbuf, bn_a, bn_b, (uint_t*)xbf, N_NODES);

    // layer 2: (150000x128 bf16) @ (128x64)
    gemm_kernel<ushort_t, 128, 64, 256><<<(N_NODES + 255) / 256, 256, 0, stream>>>(
        xbf, xbf, N_NODES, W2, hbuf, N_NODES);
    agg_kernel<64><<<AGGB, 256, 0, stream>>>(hbuf, dis, off, csr8, b2, X, N_NODES);

    // loss
    zero_float_kernel<<<1, 1, 0, stream>>>(out);
    loss_kernel<<<(BATCH + 3) / 4, 256, 0, stream>>>(X, user_id, pos_item, neg_item, out);
}

// Round 11
// 1077.346 us; speedup vs baseline: 1.0697x; 1.0697x over previous
//
#include <hip/hip_runtime.h>
#include <hip/hip_bf16.h>
#include <math.h>

#define USER_NUM 100000
#define ITEM_NUM 50000
#define N_NODES  150000
#define N_EDGES  2400000
#define OUT_DIM  64
#define HID_DIM  128
#define BATCH    4096
#define EPS_BN   1e-5f

typedef unsigned short ushort_t;
typedef unsigned int uint_t;

// fp32 -> bf16 (round-to-nearest-even), and back
__device__ __forceinline__ ushort_t f2bf(float f) {
    uint_t u = __float_as_uint(f);
    u += 0x7FFFu + ((u >> 16) & 1u);
    return (ushort_t)(u >> 16);
}
__device__ __forceinline__ float bf2f(ushort_t s) {
    return __uint_as_float((uint_t)s << 16);
}

// ---------------- preprocessing ----------------

__global__ __launch_bounds__(256) void zero_int_kernel(int* __restrict__ p, int n) {
    int i = blockIdx.x * 256 + threadIdx.x;
    if (i < n) p[i] = 0;
}

__global__ __launch_bounds__(256) void count_kernel(const int* __restrict__ dst, int* __restrict__ cnt) {
    int i = blockIdx.x * 256 + threadIdx.x;
    if (i < N_EDGES) atomicAdd(&cnt[dst[i]], 1);
}

__global__ __launch_bounds__(256) void dis_kernel(const int* __restrict__ cnt, float* __restrict__ dis) {
    int i = blockIdx.x * 256 + threadIdx.x;
    if (i < N_NODES) dis[i] = rsqrtf(1.0f + (float)cnt[i]);
}

// 3-pass scan: per-block sums -> scan of block sums -> emit offsets
#define SC_ELEM 1024
#define SC_NB   ((N_NODES + SC_ELEM - 1) / SC_ELEM)   // 147

__global__ __launch_bounds__(256) void scan_part_kernel(const int* __restrict__ cnt,
                                                        int* __restrict__ psum) {
    __shared__ int red[4];
    int tid = threadIdx.x;
    int base = blockIdx.x * SC_ELEM + tid * 4;
    int s = 0;
#pragma unroll
    for (int j = 0; j < 4; j++) { int i = base + j; if (i < N_NODES) s += cnt[i]; }
#pragma unroll
    for (int d = 1; d < 64; d <<= 1) s += __shfl_xor(s, d);
    if ((tid & 63) == 0) red[tid >> 6] = s;
    __syncthreads();
    if (tid == 0) psum[blockIdx.x] = red[0] + red[1] + red[2] + red[3];
}

__global__ __launch_bounds__(256) void scan_mid_kernel(int* __restrict__ psum,
                                                       int* __restrict__ off, int nb) {
    __shared__ int lds[256];
    int tid = threadIdx.x;
    int v = (tid < nb) ? psum[tid] : 0;
    lds[tid] = v;
    __syncthreads();
    for (int d = 1; d < 256; d <<= 1) {
        int t = (tid >= d) ? lds[tid - d] : 0;
        __syncthreads();
        lds[tid] += t;
        __syncthreads();
    }
    if (tid < nb) psum[tid] = lds[tid] - v;   // exclusive
    if (tid == 0) off[N_NODES] = lds[255];
}

__global__ __launch_bounds__(256) void scan_emit_kernel(const int* __restrict__ cnt,
                                                        const int* __restrict__ psum,
                                                        int* __restrict__ off) {
    __shared__ int lds[256];
    int tid = threadIdx.x;
    int base = blockIdx.x * SC_ELEM + tid * 4;
    int v[4]; int s = 0;
#pragma unroll
    for (int j = 0; j < 4; j++) {
        int i = base + j;
        v[j] = (i < N_NODES) ? cnt[i] : 0;
        s += v[j];
    }
    lds[tid] = s;
    __syncthreads();
    for (int d = 1; d < 256; d <<= 1) {
        int t = (tid >= d) ? lds[tid - d] : 0;
        __syncthreads();
        lds[tid] += t;
        __syncthreads();
    }
    int run = psum[blockIdx.x] + lds[tid] - s;
#pragma unroll
    for (int j = 0; j < 4; j++) {
        int i = base + j;
        if (i < N_NODES) off[i] = run;
        run += v[j];
    }
}

// ---------------- two-pass bucketed CSR build ----------------
// Bucket = dst>>9 (512 nodes, 293 buckets). Pass 1 groups edges by bucket
// into temp with per-block contiguous runs (lines written by one block,
// quickly -> write-combining works). Pass 2: one block per bucket does the
// fine scatter to exact CSR slots inside its contiguous ~65KB region.

#define BSH   9
#define NBUCK ((N_NODES + 511) / 512)     // 293
#define P1_BLOCKS 512

__global__ __launch_bounds__(256) void bucket_part_kernel(const int* __restrict__ src,
                                                          const int* __restrict__ dst,
                                                          const int* __restrict__ off,
                                                          int* __restrict__ bcur,
                                                          uint2* __restrict__ temp) {
    __shared__ int hist[NBUCK];
    __shared__ int base[NBUCK];
    const int per = (N_EDGES + P1_BLOCKS - 1) / P1_BLOCKS;   // 4688
    const int lo = blockIdx.x * per;
    int hi = lo + per; if (hi > N_EDGES) hi = N_EDGES;
    const int tid = threadIdx.x;
    for (int j = tid; j < NBUCK; j += 256) hist[j] = 0;
    __syncthreads();
    for (int i = lo + tid; i < hi; i += 256)
        atomicAdd(&hist[dst[i] >> BSH], 1);
    __syncthreads();
    for (int b = tid; b < NBUCK; b += 256) {
        int h = hist[b];
        if (h > 0) base[b] = off[b << BSH] + atomicAdd(&bcur[b], h);
    }
    __syncthreads();
    for (int i = lo + tid; i < hi; i += 256) {
        int d = dst[i];
        int p = atomicAdd(&base[d >> BSH], 1);
        temp[p] = make_uint2((uint_t)src[i], (uint_t)d);
    }
}

// CSR entry: .x = src node, .y = bit-pattern of edge weight dis[src]*dis[dst]
__global__ __launch_bounds__(256) void bucket_fine_kernel(const int* __restrict__ off,
                                                          const float* __restrict__ dis,
                                                          const uint2* __restrict__ temp,
                                                          uint2* __restrict__ csr8) {
    __shared__ int   offs[513];
    __shared__ int   cur[512];
    __shared__ float disd[512];
    const int b  = blockIdx.x;
    const int lo = b << BSH;
    int hi = lo + 512; if (hi > N_NODES) hi = N_NODES;
    const int nn = hi - lo;
    const int tid = threadIdx.x;
    for (int j = tid; j <= nn; j += 256) offs[j] = off[lo + j];
    for (int j = tid; j < nn; j += 256) { cur[j] = 0; disd[j] = dis[lo + j]; }
    __syncthreads();
    const int e0 = offs[0], e1 = offs[nn];
    for (int i = e0 + tid; i < e1; i += 256) {
        uint2 t = temp[i];
        int dl = (int)t.y - lo;
        int p = offs[dl] + atomicAdd(&cur[dl], 1);
        float wv = dis[t.x] * disd[dl];
        csr8[p] = make_uint2(t.x, __float_as_uint(wv));
    }
}

// ---------------- GEMM: out[M][DOUT] = x[M][DIN] @ W[DIN][DOUT], bf16 output ----------------
// XT = float or ushort_t (bf16) input. 256 threads, block tile MBLK x DOUT,
// micro-tile 8x8 per thread, K-chunks of 32 in LDS with reg-staged prefetch.

__device__ __forceinline__ float4 load4(const float* p) { return *(const float4*)p; }
__device__ __forceinline__ float4 load4(const ushort_t* p) {
    ushort4 u = *(const ushort4*)p;
    return make_float4(bf2f(u.x), bf2f(u.y), bf2f(u.z), bf2f(u.w));
}

template<typename XT, int DIN, int DOUT, int MBLK>
__global__ __launch_bounds__(256) void gemm_kernel(const XT* __restrict__ xlo,
                                                   const XT* __restrict__ xhi, int split,
                                                   const float* __restrict__ W,
                                                   ushort_t* __restrict__ out, int nrows) {
    constexpr int KC    = 32;
    constexpr int NC    = DIN / KC;
    constexpr int XS_PT = MBLK / 32;      // 4-elem x-loads per thread per chunk
    constexpr int WS_PT = DOUT / 32;      // float4 w-loads per thread per chunk
    constexpr int NCOLG = DOUT / 8;

    __shared__ float xs[MBLK][KC + 1];    // +1 pad: conflict-free column reads
    __shared__ float ws[KC][DOUT];

    const int tid  = threadIdx.x;
    const int row0 = blockIdx.x * MBLK;
    const int colg = tid % NCOLG;
    const int rowg = tid / NCOLG;

    float4 xr[XS_PT], wr[WS_PT];

    auto load_chunk = [&](int kc) {
#pragma unroll
        for (int i = 0; i < XS_PT; i++) {
            int idx = i * 256 + tid;
            int m = idx >> 3, kq = idx & 7;
            int row = row0 + m; if (row > nrows - 1) row = nrows - 1;
            const XT* rp = (row < split) ? xlo + (size_t)row * DIN
                                         : xhi + (size_t)(row - split) * DIN;
            xr[i] = load4(rp + kc + kq * 4);
        }
#pragma unroll
        for (int i = 0; i < WS_PT; i++) {
            int idx = i * 256 + tid;
            int n4 = idx % (DOUT / 4), kk = idx / (DOUT / 4);
            wr[i] = *(const float4*)(W + (size_t)(kc + kk) * DOUT + n4 * 4);
        }
    };
    auto write_chunk = [&]() {
#pragma unroll
        for (int i = 0; i < XS_PT; i++) {
            int idx = i * 256 + tid;
            int m = idx >> 3, kq = idx & 7;
            xs[m][kq * 4 + 0] = xr[i].x;
            xs[m][kq * 4 + 1] = xr[i].y;
            xs[m][kq * 4 + 2] = xr[i].z;
            xs[m][kq * 4 + 3] = xr[i].w;
        }
#pragma unroll
        for (int i = 0; i < WS_PT; i++) {
            int idx = i * 256 + tid;
            int n4 = idx % (DOUT / 4), kk = idx / (DOUT / 4);
            *(float4*)&ws[kk][n4 * 4] = wr[i];
        }
    };

    float acc[8][8];
#pragma unroll
    for (int r = 0; r < 8; r++)
#pragma unroll
        for (int c = 0; c < 8; c++) acc[r][c] = 0.f;

    load_chunk(0);
    write_chunk();
    __syncthreads();

    for (int c = 0; c < NC; c++) {
        if (c + 1 < NC) load_chunk((c + 1) * KC);   // prefetch under compute
#pragma unroll 4
        for (int k = 0; k < KC; k++) {
            float4 wa = *(const float4*)&ws[k][colg * 8];
            float4 wb = *(const float4*)&ws[k][colg * 8 + 4];
            float xv[8];
#pragma unroll
            for (int r = 0; r < 8; r++) xv[r] = xs[rowg * 8 + r][k];
#pragma unroll
            for (int r = 0; r < 8; r++) {
                acc[r][0] = fmaf(xv[r], wa.x, acc[r][0]);
                acc[r][1] = fmaf(xv[r], wa.y, acc[r][1]);
                acc[r][2] = fmaf(xv[r], wa.z, acc[r][2]);
                acc[r][3] = fmaf(xv[r], wa.w, acc[r][3]);
                acc[r][4] = fmaf(xv[r], wb.x, acc[r][4]);
                acc[r][5] = fmaf(xv[r], wb.y, acc[r][5]);
                acc[r][6] = fmaf(xv[r], wb.z, acc[r][6]);
                acc[r][7] = fmaf(xv[r], wb.w, acc[r][7]);
            }
        }
        __syncthreads();
        if (c + 1 < NC) { write_chunk(); __syncthreads(); }
    }

#pragma unroll
    for (int r = 0; r < 8; r++) {
        int row = row0 + rowg * 8 + r;
        if (row < nrows) {
            uint4 pk;
            pk.x = (uint_t)f2bf(acc[r][0]) | ((uint_t)f2bf(acc[r][1]) << 16);
            pk.y = (uint_t)f2bf(acc[r][2]) | ((uint_t)f2bf(acc[r][3]) << 16);
            pk.z = (uint_t)f2bf(acc[r][4]) | ((uint_t)f2bf(acc[r][5]) << 16);
            pk.w = (uint_t)f2bf(acc[r][6]) | ((uint_t)f2bf(acc[r][7]) << 16);
            *(uint4*)&out[(size_t)row * DOUT + colg * 8] = pk;
        }
    }
}

// ---------------- edge aggregation (CSR gather over bf16 h, one wave per node) ----------------
// out[i] = sum_e w_e*h[s_e] + h[i]*dis[i]^2 + bias   (fp32 accumulate/output)

template<int DOUT>
__global__ __launch_bounds__(256) void agg_kernel(const ushort_t* __restrict__ h,
                                                  const float* __restrict__ dis,
                                                  const int* __restrict__ off,
                                                  const uint2* __restrict__ csr8,
                                                  const float* __restrict__ bias,
                                                  float* __restrict__ out, int n) {
    int wave = threadIdx.x >> 6;
    int lane = threadIdx.x & 63;
    int node = blockIdx.x * 4 + wave;
    if (node >= n) return;
    float di  = dis[node];
    int   beg = off[node], end = off[node + 1];
    if (DOUT == 128) {
        const uint_t* hp = (const uint_t*)h;   // 64 uints (128 bf16) per row
        float ax = 0.f, ay = 0.f;
        int e = beg;
        for (; e + 4 <= end; e += 4) {
            uint2 e0 = csr8[e], e1 = csr8[e + 1], e2 = csr8[e + 2], e3 = csr8[e + 3];
            uint_t u0 = hp[(size_t)e0.x * 64 + lane];
            uint_t u1 = hp[(size_t)e1.x * 64 + lane];
            uint_t u2 = hp[(size_t)e2.x * 64 + lane];
            uint_t u3 = hp[(size_t)e3.x * 64 + lane];
            float w0 = __uint_as_float(e0.y), w1 = __uint_as_float(e1.y);
            float w2 = __uint_as_float(e2.y), w3 = __uint_as_float(e3.y);
            ax = fmaf(__uint_as_float(u0 << 16), w0, ax);
            ay = fmaf(__uint_as_float(u0 & 0xFFFF0000u), w0, ay);
            ax = fmaf(__uint_as_float(u1 << 16), w1, ax);
            ay = fmaf(__uint_as_float(u1 & 0xFFFF0000u), w1, ay);
            ax = fmaf(__uint_as_float(u2 << 16), w2, ax);
            ay = fmaf(__uint_as_float(u2 & 0xFFFF0000u), w2, ay);
            ax = fmaf(__uint_as_float(u3 << 16), w3, ax);
            ay = fmaf(__uint_as_float(u3 & 0xFFFF0000u), w3, ay);
        }
        for (; e < end; e++) {
            uint2 ev = csr8[e];
            float wv = __uint_as_float(ev.y);
            uint_t u = hp[(size_t)ev.x * 64 + lane];
            ax = fmaf(__uint_as_float(u << 16), wv, ax);
            ay = fmaf(__uint_as_float(u & 0xFFFF0000u), wv, ay);
        }
        uint_t us = hp[(size_t)node * 64 + lane];
        float2 bb = ((const float2*)bias)[lane];
        float dd = di * di;
        float2 o;
        o.x = ax + __uint_as_float(us << 16) * dd + bb.x;
        o.y = ay + __uint_as_float(us & 0xFFFF0000u) * dd + bb.y;
        ((float2*)out)[(size_t)node * 64 + lane] = o;
    } else {
        float ax = 0.f;
        int e = beg;
        for (; e + 4 <= end; e += 4) {
            uint2 e0 = csr8[e], e1 = csr8[e + 1], e2 = csr8[e + 2], e3 = csr8[e + 3];
            float h0 = bf2f(h[(size_t)e0.x * 64 + lane]);
            float h1 = bf2f(h[(size_t)e1.x * 64 + lane]);
            float h2 = bf2f(h[(size_t)e2.x * 64 + lane]);
            float h3 = bf2f(h[(size_t)e3.x * 64 + lane]);
            ax = fmaf(h0, __uint_as_float(e0.y), ax);
            ax = fmaf(h1, __uint_as_float(e1.y), ax);
            ax = fmaf(h2, __uint_as_float(e2.y), ax);
            ax = fmaf(h3, __uint_as_float(e3.y), ax);
        }
        for (; e < end; e++) {
            uint2 ev = csr8[e];
            ax = fmaf(bf2f(h[(size_t)ev.x * 64 + lane]), __uint_as_float(ev.y), ax);
        }
        float hs = bf2f(h[(size_t)node * 64 + lane]);
        out[(size_t)node * 64 + lane] = ax + hs * di * di + bias[lane];
    }
}

// ---------------- BN stats (two-stage, double partials) ----------------

#define STATS_NB 512

__global__ __launch_bounds__(128) void stats1_kernel(const float* __restrict__ x,
                                                     double* __restrict__ part) {
    int col = threadIdx.x;
    double a = 0.0, b = 0.0;
    for (int row = blockIdx.x; row < N_NODES; row += STATS_NB) {
        float v = x[(size_t)row * HID_DIM + col];
        a += v;
        b += (double)v * (double)v;
    }
    part[(size_t)blockIdx.x * 256 + col]       = a;
    part[(size_t)blockIdx.x * 256 + 128 + col] = b;
}

// parallel final reduce: one block per column, 256 threads sweep the partials
__global__ __launch_bounds__(256) void stats2_kernel(const double* __restrict__ part,
                                                     const float* __restrict__ g,
                                                     const float* __restrict__ beta,
                                                     float* __restrict__ a_out,
                                                     float* __restrict__ b_out) {
    __shared__ double red1[4], red2[4];
    int col = blockIdx.x;       // 0..127
    int tid = threadIdx.x;
    double s1 = 0.0, s2 = 0.0;
    for (int p = tid; p < STATS_NB; p += 256) {
        s1 += part[(size_t)p * 256 + col];
        s2 += part[(size_t)p * 256 + 128 + col];
    }
#pragma unroll
    for (int d = 32; d >= 1; d >>= 1) {
        s1 += __shfl_xor(s1, d);
        s2 += __shfl_xor(s2, d);
    }
    int wave = tid >> 6, lane = tid & 63;
    if (lane == 0) { red1[wave] = s1; red2[wave] = s2; }
    __syncthreads();
    if (tid == 0) {
        double t1 = red1[0] + red1[1] + red1[2] + red1[3];
        double t2 = red2[0] + red2[1] + red2[2] + red2[3];
        double mean = t1 / (double)N_NODES;
        double var  = t2 / (double)N_NODES - mean * mean;
        float inv = rsqrtf((float)var + EPS_BN);
        float aa  = g[col] * inv;
        a_out[col] = aa;
        b_out[col] = beta[col] - (float)mean * aa;
    }
}

// ---------------- fused BN-apply + ReLU + row L2-norm -> bf16 (wave per row) ----------------

__global__ __launch_bounds__(256) void bn_relu_l2_kernel(const float* __restrict__ in,
                                                         const float* __restrict__ a,
                                                         const float* __restrict__ b,
                                                         uint_t* __restrict__ outp, int n) {
    int wave = threadIdx.x >> 6;
    int lane = threadIdx.x & 63;
    int row  = blockIdx.x * 4 + wave;
    if (row >= n) return;
    float2 v  = *(const float2*)(in + (size_t)row * 128 + lane * 2);
    float2 aa = *(const float2*)(a + lane * 2);
    float2 bb = *(const float2*)(b + lane * 2);
    float y0 = fmaxf(fmaf(v.x, aa.x, bb.x), 0.f);
    float y1 = fmaxf(fmaf(v.y, aa.y, bb.y), 0.f);
    float ss = y0 * y0 + y1 * y1;
#pragma unroll
    for (int d = 32; d >= 1; d >>= 1) ss += __shfl_xor(ss, d);
    float nn  = sqrtf(ss);
    float inv = 1.f / fmaxf(nn, 1e-12f);
    uint_t pk = (uint_t)f2bf(y0 * inv) | ((uint_t)f2bf(y1 * inv) << 16);
    outp[(size_t)row * 64 + lane] = pk;
}

// ---------------- loss ----------------

__global__ void zero_float_kernel(float* p) { *p = 0.f; }

__global__ __launch_bounds__(256) void loss_kernel(const float* __restrict__ X,
                                                   const int* __restrict__ uid,
                                                   const int* __restrict__ pid,
                                                   const int* __restrict__ nid,
                                                   float* __restrict__ out0) {
    int wave = threadIdx.x >> 6;
    int lane = threadIdx.x & 63;
    int b = blockIdx.x * 4 + wave;
    if (b >= BATCH) return;
    const float* u = X + (size_t)uid[b] * OUT_DIM;
    const float* p = X + (size_t)(USER_NUM + pid[b]) * OUT_DIM;
    const float* q = X + (size_t)(USER_NUM + nid[b]) * OUT_DIM;
    float uv = u[lane];
    float ps = uv * p[lane];
    float ns = uv * q[lane];
#pragma unroll
    for (int d = 32; d >= 1; d >>= 1) {
        ps += __shfl_xor(ps, d);
        ns += __shfl_xor(ns, d);
    }
    if (lane == 0) {
        float t  = ns - ps;                                   // -(pos - neg)
        float sp = fmaxf(t, 0.f) + log1pf(expf(-fabsf(t)));   // softplus(t)
        atomicAdd(out0, sp * (1.0f / BATCH));
    }
}

// ---------------- launch ----------------

extern "C" void kernel_launch(void* const* d_in, const int* in_sizes, int n_in,
                              void* d_out, int out_size, void* d_ws, size_t ws_size,
                              hipStream_t stream) {
    const float* user_emb = (const float*)d_in[0];
    const float* item_emb = (const float*)d_in[1];
    const float* W0  = (const float*)d_in[2];
    const float* b0  = (const float*)d_in[3];
    const float* g0  = (const float*)d_in[4];
    const float* be0 = (const float*)d_in[5];
    const float* W1  = (const float*)d_in[6];
    const float* b1  = (const float*)d_in[7];
    const float* g1  = (const float*)d_in[8];
    const float* be1 = (const float*)d_in[9];
    const float* W2  = (const float*)d_in[10];
    const float* b2  = (const float*)d_in[11];
    const int* user_id  = (const int*)d_in[12];
    const int* pos_item = (const int*)d_in[13];
    const int* neg_item = (const int*)d_in[14];
    const int* edge     = (const int*)d_in[15];
    const int* src = edge;
    const int* dst = edge + N_EDGES;

    char* w = (char*)d_ws;
    auto alloc = [&](size_t bytes) -> char* {
        char* r = w;
        w += (bytes + 255) / 256 * 256;
        return r;
    };
    int*      cnt  = (int*)alloc((size_t)N_NODES * 4);
    int*      off  = (int*)alloc((size_t)(N_NODES + 1) * 4);
    int*      bcur = (int*)alloc((size_t)NBUCK * 4);
    uint2*    csr8 = (uint2*)alloc((size_t)N_EDGES * 8);
    float*    dis  = (float*)alloc((size_t)N_NODES * 4);
    int*      psum = (int*)alloc((size_t)SC_NB * 4);
    double*   part = (double*)alloc((size_t)STATS_NB * 256 * 8);
    float*    bn_a = (float*)alloc(128 * 4);
    float*    bn_b = (float*)alloc(128 * 4);
    ushort_t* hbuf = (ushort_t*)alloc((size_t)N_NODES * HID_DIM * 2);   // bf16 GEMM output
    float*    xbuf = (float*)alloc((size_t)N_NODES * HID_DIM * 4);      // fp32 agg output
    ushort_t* xbf  = (ushort_t*)alloc((size_t)N_NODES * HID_DIM * 2);   // bf16 normalized x

    // temp edge buffer for bucket pass reuses hbuf (38.4MB >= 19.2MB needed;
    // hbuf is first written by gemm0 AFTER the CSR build completes in-stream)
    uint2* temp = (uint2*)hbuf;

    float* out = (float*)d_out;
    float* X   = out + 1;   // node embeddings region (150000 x 64)

    const int EB = (N_EDGES + 255) / 256;
    const int NB = (N_NODES + 255) / 256;
    const int AGGB = (N_NODES + 3) / 4;

    // preprocessing: degree, dis, CSR via bucketed two-pass build
    zero_int_kernel<<<NB, 256, 0, stream>>>(cnt, N_NODES);
    count_kernel<<<EB, 256, 0, stream>>>(dst, cnt);
    dis_kernel<<<NB, 256, 0, stream>>>(cnt, dis);
    scan_part_kernel<<<SC_NB, 256, 0, stream>>>(cnt, psum);
    scan_mid_kernel<<<1, 256, 0, stream>>>(psum, off, SC_NB);
    scan_emit_kernel<<<SC_NB, 256, 0, stream>>>(cnt, psum, off);
    zero_int_kernel<<<(NBUCK + 255) / 256, 256, 0, stream>>>(bcur, NBUCK);
    bucket_part_kernel<<<P1_BLOCKS, 256, 0, stream>>>(src, dst, off, bcur, temp);
    bucket_fine_kernel<<<NBUCK, 256, 0, stream>>>(off, dis, temp, csr8);

    // layer 0: (150000x64 fp32) @ (64x128)
    gemm_kernel<float, 64, 128, 128><<<(N_NODES + 127) / 128, 256, 0, stream>>>(
        user_emb, item_emb, USER_NUM, W0, hbuf, N_NODES);
    agg_kernel<128><<<AGGB, 256, 0, stream>>>(hbuf, dis, off, csr8, b0, xbuf, N_NODES);
    stats1_kernel<<<STATS_NB, 128, 0, stream>>>(xbuf, part);
    stats2_kernel<<<128, 256, 0, stream>>>(part, g0, be0, bn_a, bn_b);
    bn_relu_l2_kernel<<<AGGB, 256, 0, stream>>>(xbuf, bn_a, bn_b, (uint_t*)xbf, N_NODES);

    // layer 1: (150000x128 bf16) @ (128x128)
    gemm_kernel<ushort_t, 128, 128, 128><<<(N_NODES + 127) / 128, 256, 0, stream>>>(
        xbf, xbf, N_NODES, W1, hbuf, N_NODES);
    agg_kernel<128><<<AGGB, 256, 0, stream>>>(hbuf, dis, off, csr8, b1, xbuf, N_NODES);
    stats1_kernel<<<STATS_NB, 128, 0, stream>>>(xbuf, part);
    stats2_kernel<<<128, 256, 0, stream>>>(part, g1, be1, bn_a, bn_b);
    bn_relu_l2_kernel<<<AGGB, 256, 0, stream>>>(xbuf, bn_a, bn_b, (uint_t*)xbf, N_NODES);

    // layer 2: (150000x128 bf16) @ (128x64)
    gemm_kernel<ushort_t, 128, 64, 256><<<(N_NODES + 255) / 256, 256, 0, stream>>>(
        xbf, xbf, N_NODES, W2, hbuf, N_NODES);
    agg_kernel<64><<<AGGB, 256, 0, stream>>>(hbuf, dis, off, csr8, b2, X, N_NODES);

    // loss
    zero_float_kernel<<<1, 1, 0, stream>>>(out);
    loss_kernel<<<(BATCH + 3) / 4, 256, 0, stream>>>(X, user_id, pos_item, neg_item, out);
}

// Round 12
// 967.489 us; speedup vs baseline: 1.1911x; 1.1135x over previous
//
#include <hip/hip_runtime.h>
#include <hip/hip_bf16.h>
#include <math.h>

#define USER_NUM 100000
#define ITEM_NUM 50000
#define N_NODES  150000
#define N_EDGES  2400000
#define OUT_DIM  64
#define HID_DIM  128
#define BATCH    4096
#define EPS_BN   1e-5f

typedef unsigned short ushort_t;
typedef unsigned int uint_t;

typedef __attribute__((ext_vector_type(8))) __bf16 bf16x8;
typedef __attribute__((ext_vector_type(4))) float f32x4;

// fp32 -> bf16 (round-to-nearest-even), and back
__device__ __forceinline__ ushort_t f2bf(float f) {
    uint_t u = __float_as_uint(f);
    u += 0x7FFFu + ((u >> 16) & 1u);
    return (ushort_t)(u >> 16);
}
__device__ __forceinline__ float bf2f(ushort_t s) {
    return __uint_as_float((uint_t)s << 16);
}

// ---------------- preprocessing ----------------

__global__ __launch_bounds__(256) void zero_int_kernel(int* __restrict__ p, int n) {
    int i = blockIdx.x * 256 + threadIdx.x;
    if (i < n) p[i] = 0;
}

__global__ __launch_bounds__(256) void count_kernel(const int* __restrict__ dst, int* __restrict__ cnt) {
    int i = blockIdx.x * 256 + threadIdx.x;
    if (i < N_EDGES) atomicAdd(&cnt[dst[i]], 1);
}

__global__ __launch_bounds__(256) void dis_kernel(const int* __restrict__ cnt, float* __restrict__ dis) {
    int i = blockIdx.x * 256 + threadIdx.x;
    if (i < N_NODES) dis[i] = rsqrtf(1.0f + (float)cnt[i]);
}

// 3-pass scan: per-block sums -> scan of block sums -> emit offsets
#define SC_ELEM 1024
#define SC_NB   ((N_NODES + SC_ELEM - 1) / SC_ELEM)   // 147

__global__ __launch_bounds__(256) void scan_part_kernel(const int* __restrict__ cnt,
                                                        int* __restrict__ psum) {
    __shared__ int red[4];
    int tid = threadIdx.x;
    int base = blockIdx.x * SC_ELEM + tid * 4;
    int s = 0;
#pragma unroll
    for (int j = 0; j < 4; j++) { int i = base + j; if (i < N_NODES) s += cnt[i]; }
#pragma unroll
    for (int d = 1; d < 64; d <<= 1) s += __shfl_xor(s, d);
    if ((tid & 63) == 0) red[tid >> 6] = s;
    __syncthreads();
    if (tid == 0) psum[blockIdx.x] = red[0] + red[1] + red[2] + red[3];
}

__global__ __launch_bounds__(256) void scan_mid_kernel(int* __restrict__ psum,
                                                       int* __restrict__ off, int nb) {
    __shared__ int lds[256];
    int tid = threadIdx.x;
    int v = (tid < nb) ? psum[tid] : 0;
    lds[tid] = v;
    __syncthreads();
    for (int d = 1; d < 256; d <<= 1) {
        int t = (tid >= d) ? lds[tid - d] : 0;
        __syncthreads();
        lds[tid] += t;
        __syncthreads();
    }
    if (tid < nb) psum[tid] = lds[tid] - v;   // exclusive
    if (tid == 0) off[N_NODES] = lds[255];
}

__global__ __launch_bounds__(256) void scan_emit_kernel(const int* __restrict__ cnt,
                                                        const int* __restrict__ psum,
                                                        int* __restrict__ off) {
    __shared__ int lds[256];
    int tid = threadIdx.x;
    int base = blockIdx.x * SC_ELEM + tid * 4;
    int v[4]; int s = 0;
#pragma unroll
    for (int j = 0; j < 4; j++) {
        int i = base + j;
        v[j] = (i < N_NODES) ? cnt[i] : 0;
        s += v[j];
    }
    lds[tid] = s;
    __syncthreads();
    for (int d = 1; d < 256; d <<= 1) {
        int t = (tid >= d) ? lds[tid - d] : 0;
        __syncthreads();
        lds[tid] += t;
        __syncthreads();
    }
    int run = psum[blockIdx.x] + lds[tid] - s;
#pragma unroll
    for (int j = 0; j < 4; j++) {
        int i = base + j;
        if (i < N_NODES) off[i] = run;
        run += v[j];
    }
}

// ---------------- two-pass bucketed CSR build ----------------
// Bucket = dst>>9 (512 nodes, 293 buckets). Pass 1 groups edges by bucket
// into temp with per-block contiguous runs (lines written by one block,
// quickly -> write-combining works). Pass 2: one block per bucket does the
// fine scatter to exact CSR slots inside its contiguous ~65KB region.

#define BSH   9
#define NBUCK ((N_NODES + 511) / 512)     // 293
#define P1_BLOCKS 512

__global__ __launch_bounds__(256) void bucket_part_kernel(const int* __restrict__ src,
                                                          const int* __restrict__ dst,
                                                          const int* __restrict__ off,
                                                          int* __restrict__ bcur,
                                                          uint2* __restrict__ temp) {
    __shared__ int hist[NBUCK];
    __shared__ int base[NBUCK];
    const int per = (N_EDGES + P1_BLOCKS - 1) / P1_BLOCKS;   // 4688
    const int lo = blockIdx.x * per;
    int hi = lo + per; if (hi > N_EDGES) hi = N_EDGES;
    const int tid = threadIdx.x;
    for (int j = tid; j < NBUCK; j += 256) hist[j] = 0;
    __syncthreads();
    for (int i = lo + tid; i < hi; i += 256)
        atomicAdd(&hist[dst[i] >> BSH], 1);
    __syncthreads();
    for (int b = tid; b < NBUCK; b += 256) {
        int h = hist[b];
        if (h > 0) base[b] = off[b << BSH] + atomicAdd(&bcur[b], h);
    }
    __syncthreads();
    for (int i = lo + tid; i < hi; i += 256) {
        int d = dst[i];
        int p = atomicAdd(&base[d >> BSH], 1);
        temp[p] = make_uint2((uint_t)src[i], (uint_t)d);
    }
}

// CSR entry: .x = src node, .y = bit-pattern of edge weight dis[src]*dis[dst]
__global__ __launch_bounds__(256) void bucket_fine_kernel(const int* __restrict__ off,
                                                          const float* __restrict__ dis,
                                                          const uint2* __restrict__ temp,
                                                          uint2* __restrict__ csr8) {
    __shared__ int   offs[513];
    __shared__ int   cur[512];
    __shared__ float disd[512];
    const int b  = blockIdx.x;
    const int lo = b << BSH;
    int hi = lo + 512; if (hi > N_NODES) hi = N_NODES;
    const int nn = hi - lo;
    const int tid = threadIdx.x;
    for (int j = tid; j <= nn; j += 256) offs[j] = off[lo + j];
    for (int j = tid; j < nn; j += 256) { cur[j] = 0; disd[j] = dis[lo + j]; }
    __syncthreads();
    const int e0 = offs[0], e1 = offs[nn];
    for (int i = e0 + tid; i < e1; i += 256) {
        uint2 t = temp[i];
        int dl = (int)t.y - lo;
        int p = offs[dl] + atomicAdd(&cur[dl], 1);
        float wv = dis[t.x] * disd[dl];
        csr8[p] = make_uint2(t.x, __float_as_uint(wv));
    }
}

// ---------------- MFMA GEMM: out[M][DOUT] = x[M][DIN] @ W[DIN][DOUT], bf16 out --------------
// mfma_f32_16x16x32_bf16. 4 waves x 32 rows = 128 rows/block. W staged
// transposed in LDS as bf16 (+8 pad: 16B-aligned ds_read_b128 B-frags).
// A loaded directly from global (16B/lane). fp32 inputs converted on load.

__device__ __forceinline__ bf16x8 loadA(const ushort_t* p) {
    uint4 u = *(const uint4*)p;
    return __builtin_bit_cast(bf16x8, u);
}
__device__ __forceinline__ bf16x8 loadA(const float* p) {
    float4 f0 = *(const float4*)p;
    float4 f1 = *(const float4*)(p + 4);
    uint4 u;
    u.x = (uint_t)f2bf(f0.x) | ((uint_t)f2bf(f0.y) << 16);
    u.y = (uint_t)f2bf(f0.z) | ((uint_t)f2bf(f0.w) << 16);
    u.z = (uint_t)f2bf(f1.x) | ((uint_t)f2bf(f1.y) << 16);
    u.w = (uint_t)f2bf(f1.z) | ((uint_t)f2bf(f1.w) << 16);
    return __builtin_bit_cast(bf16x8, u);
}

template<typename XT, int DIN, int DOUT>
__global__ __launch_bounds__(256) void gemm_kernel(const XT* __restrict__ xlo,
                                                   const XT* __restrict__ xhi, int split,
                                                   const float* __restrict__ W,
                                                   ushort_t* __restrict__ out, int nrows) {
    constexpr int LDW = DIN + 8;                  // padded row (elems), 16B-aligned rows
    constexpr int NCT = DOUT / 16;                // column tiles
    __shared__ ushort_t wt[DOUT][LDW];            // W^T, bf16 bits

    const int tid = threadIdx.x;
    for (int idx = tid; idx < DIN * DOUT; idx += 256) {
        int k = idx / DOUT, n = idx % DOUT;
        wt[n][k] = f2bf(W[idx]);
    }
    __syncthreads();

    const int wave = tid >> 6, lane = tid & 63;
    const int lm = lane & 15, lk = lane >> 4;     // row-in-tile, k-group
    const int row0 = blockIdx.x * 128 + wave * 32;

    f32x4 acc[2][NCT];
#pragma unroll
    for (int rt = 0; rt < 2; rt++)
#pragma unroll
        for (int c = 0; c < NCT; c++) acc[rt][c] = (f32x4){0.f, 0.f, 0.f, 0.f};

    const XT* rp[2];
#pragma unroll
    for (int rt = 0; rt < 2; rt++) {
        int row = row0 + rt * 16 + lm;
        if (row > nrows - 1) row = nrows - 1;
        rp[rt] = (row < split) ? xlo + (size_t)row * DIN
                               : xhi + (size_t)(row - split) * DIN;
    }

#pragma unroll
    for (int ks = 0; ks < DIN / 32; ks++) {
        bf16x8 a0 = loadA(rp[0] + ks * 32 + lk * 8);
        bf16x8 a1 = loadA(rp[1] + ks * 32 + lk * 8);
#pragma unroll
        for (int c = 0; c < NCT; c++) {
            bf16x8 b = *(const bf16x8*)&wt[c * 16 + lm][ks * 32 + lk * 8];
            acc[0][c] = __builtin_amdgcn_mfma_f32_16x16x32_bf16(a0, b, acc[0][c], 0, 0, 0);
            acc[1][c] = __builtin_amdgcn_mfma_f32_16x16x32_bf16(a1, b, acc[1][c], 0, 0, 0);
        }
    }

    // C/D layout: col = lane&15, row = (lane>>4)*4 + r
#pragma unroll
    for (int rt = 0; rt < 2; rt++) {
#pragma unroll
        for (int r = 0; r < 4; r++) {
            int row = row0 + rt * 16 + lk * 4 + r;
            if (row < nrows) {
#pragma unroll
                for (int c = 0; c < NCT; c++)
                    out[(size_t)row * DOUT + c * 16 + lm] = f2bf(acc[rt][c][r]);
            }
        }
    }
}

// ---------------- edge aggregation (CSR gather over bf16 h, one wave per node) ----------------
// out[i] = sum_e w_e*h[s_e] + h[i]*dis[i]^2 + bias   (fp32 accumulate/output)

template<int DOUT>
__global__ __launch_bounds__(256) void agg_kernel(const ushort_t* __restrict__ h,
                                                  const float* __restrict__ dis,
                                                  const int* __restrict__ off,
                                                  const uint2* __restrict__ csr8,
                                                  const float* __restrict__ bias,
                                                  float* __restrict__ out, int n) {
    int wave = threadIdx.x >> 6;
    int lane = threadIdx.x & 63;
    int node = blockIdx.x * 4 + wave;
    if (node >= n) return;
    float di  = dis[node];
    int   beg = off[node], end = off[node + 1];
    if (DOUT == 128) {
        const uint_t* hp = (const uint_t*)h;   // 64 uints (128 bf16) per row
        float ax = 0.f, ay = 0.f;
        int e = beg;
        for (; e + 4 <= end; e += 4) {
            uint2 e0 = csr8[e], e1 = csr8[e + 1], e2 = csr8[e + 2], e3 = csr8[e + 3];
            uint_t u0 = hp[(size_t)e0.x * 64 + lane];
            uint_t u1 = hp[(size_t)e1.x * 64 + lane];
            uint_t u2 = hp[(size_t)e2.x * 64 + lane];
            uint_t u3 = hp[(size_t)e3.x * 64 + lane];
            float w0 = __uint_as_float(e0.y), w1 = __uint_as_float(e1.y);
            float w2 = __uint_as_float(e2.y), w3 = __uint_as_float(e3.y);
            ax = fmaf(__uint_as_float(u0 << 16), w0, ax);
            ay = fmaf(__uint_as_float(u0 & 0xFFFF0000u), w0, ay);
            ax = fmaf(__uint_as_float(u1 << 16), w1, ax);
            ay = fmaf(__uint_as_float(u1 & 0xFFFF0000u), w1, ay);
            ax = fmaf(__uint_as_float(u2 << 16), w2, ax);
            ay = fmaf(__uint_as_float(u2 & 0xFFFF0000u), w2, ay);
            ax = fmaf(__uint_as_float(u3 << 16), w3, ax);
            ay = fmaf(__uint_as_float(u3 & 0xFFFF0000u), w3, ay);
        }
        for (; e < end; e++) {
            uint2 ev = csr8[e];
            float wv = __uint_as_float(ev.y);
            uint_t u = hp[(size_t)ev.x * 64 + lane];
            ax = fmaf(__uint_as_float(u << 16), wv, ax);
            ay = fmaf(__uint_as_float(u & 0xFFFF0000u), wv, ay);
        }
        uint_t us = hp[(size_t)node * 64 + lane];
        float2 bb = ((const float2*)bias)[lane];
        float dd = di * di;
        float2 o;
        o.x = ax + __uint_as_float(us << 16) * dd + bb.x;
        o.y = ay + __uint_as_float(us & 0xFFFF0000u) * dd + bb.y;
        ((float2*)out)[(size_t)node * 64 + lane] = o;
    } else {
        float ax = 0.f;
        int e = beg;
        for (; e + 4 <= end; e += 4) {
            uint2 e0 = csr8[e], e1 = csr8[e + 1], e2 = csr8[e + 2], e3 = csr8[e + 3];
            float h0 = bf2f(h[(size_t)e0.x * 64 + lane]);
            float h1 = bf2f(h[(size_t)e1.x * 64 + lane]);
            float h2 = bf2f(h[(size_t)e2.x * 64 + lane]);
            float h3 = bf2f(h[(size_t)e3.x * 64 + lane]);
            ax = fmaf(h0, __uint_as_float(e0.y), ax);
            ax = fmaf(h1, __uint_as_float(e1.y), ax);
            ax = fmaf(h2, __uint_as_float(e2.y), ax);
            ax = fmaf(h3, __uint_as_float(e3.y), ax);
        }
        for (; e < end; e++) {
            uint2 ev = csr8[e];
            ax = fmaf(bf2f(h[(size_t)ev.x * 64 + lane]), __uint_as_float(ev.y), ax);
        }
        float hs = bf2f(h[(size_t)node * 64 + lane]);
        out[(size_t)node * 64 + lane] = ax + hs * di * di + bias[lane];
    }
}

// ---------------- BN stats (two-stage, double partials) ----------------

#define STATS_NB 512

__global__ __launch_bounds__(128) void stats1_kernel(const float* __restrict__ x,
                                                     double* __restrict__ part) {
    int col = threadIdx.x;
    double a = 0.0, b = 0.0;
    for (int row = blockIdx.x; row < N_NODES; row += STATS_NB) {
        float v = x[(size_t)row * HID_DIM + col];
        a += v;
        b += (double)v * (double)v;
    }
    part[(size_t)blockIdx.x * 256 + col]       = a;
    part[(size_t)blockIdx.x * 256 + 128 + col] = b;
}

// parallel final reduce: one block per column, 256 threads sweep the partials
__global__ __launch_bounds__(256) void stats2_kernel(const double* __restrict__ part,
                                                     const float* __restrict__ g,
                                                     const float* __restrict__ beta,
                                                     float* __restrict__ a_out,
                                                     float* __restrict__ b_out) {
    __shared__ double red1[4], red2[4];
    int col = blockIdx.x;       // 0..127
    int tid = threadIdx.x;
    double s1 = 0.0, s2 = 0.0;
    for (int p = tid; p < STATS_NB; p += 256) {
        s1 += part[(size_t)p * 256 + col];
        s2 += part[(size_t)p * 256 + 128 + col];
    }
#pragma unroll
    for (int d = 32; d >= 1; d >>= 1) {
        s1 += __shfl_xor(s1, d);
        s2 += __shfl_xor(s2, d);
    }
    int wave = tid >> 6, lane = tid & 63;
    if (lane == 0) { red1[wave] = s1; red2[wave] = s2; }
    __syncthreads();
    if (tid == 0) {
        double t1 = red1[0] + red1[1] + red1[2] + red1[3];
        double t2 = red2[0] + red2[1] + red2[2] + red2[3];
        double mean = t1 / (double)N_NODES;
        double var  = t2 / (double)N_NODES - mean * mean;
        float inv = rsqrtf((float)var + EPS_BN);
        float aa  = g[col] * inv;
        a_out[col] = aa;
        b_out[col] = beta[col] - (float)mean * aa;
    }
}

// ---------------- fused BN-apply + ReLU + row L2-norm -> bf16 (wave per row) ----------------

__global__ __launch_bounds__(256) void bn_relu_l2_kernel(const float* __restrict__ in,
                                                         const float* __restrict__ a,
                                                         const float* __restrict__ b,
                                                         uint_t* __restrict__ outp, int n) {
    int wave = threadIdx.x >> 6;
    int lane = threadIdx.x & 63;
    int row  = blockIdx.x * 4 + wave;
    if (row >= n) return;
    float2 v  = *(const float2*)(in + (size_t)row * 128 + lane * 2);
    float2 aa = *(const float2*)(a + lane * 2);
    float2 bb = *(const float2*)(b + lane * 2);
    float y0 = fmaxf(fmaf(v.x, aa.x, bb.x), 0.f);
    float y1 = fmaxf(fmaf(v.y, aa.y, bb.y), 0.f);
    float ss = y0 * y0 + y1 * y1;
#pragma unroll
    for (int d = 32; d >= 1; d >>= 1) ss += __shfl_xor(ss, d);
    float nn  = sqrtf(ss);
    float inv = 1.f / fmaxf(nn, 1e-12f);
    uint_t pk = (uint_t)f2bf(y0 * inv) | ((uint_t)f2bf(y1 * inv) << 16);
    outp[(size_t)row * 64 + lane] = pk;
}

// ---------------- loss ----------------

__global__ void zero_float_kernel(float* p) { *p = 0.f; }

__global__ __launch_bounds__(256) void loss_kernel(const float* __restrict__ X,
                                                   const int* __restrict__ uid,
                                                   const int* __restrict__ pid,
                                                   const int* __restrict__ nid,
                                                   float* __restrict__ out0) {
    int wave = threadIdx.x >> 6;
    int lane = threadIdx.x & 63;
    int b = blockIdx.x * 4 + wave;
    if (b >= BATCH) return;
    const float* u = X + (size_t)uid[b] * OUT_DIM;
    const float* p = X + (size_t)(USER_NUM + pid[b]) * OUT_DIM;
    const float* q = X + (size_t)(USER_NUM + nid[b]) * OUT_DIM;
    float uv = u[lane];
    float ps = uv * p[lane];
    float ns = uv * q[lane];
#pragma unroll
    for (int d = 32; d >= 1; d >>= 1) {
        ps += __shfl_xor(ps, d);
        ns += __shfl_xor(ns, d);
    }
    if (lane == 0) {
        float t  = ns - ps;                                   // -(pos - neg)
        float sp = fmaxf(t, 0.f) + log1pf(expf(-fabsf(t)));   // softplus(t)
        atomicAdd(out0, sp * (1.0f / BATCH));
    }
}

// ---------------- launch ----------------

extern "C" void kernel_launch(void* const* d_in, const int* in_sizes, int n_in,
                              void* d_out, int out_size, void* d_ws, size_t ws_size,
                              hipStream_t stream) {
    const float* user_emb = (const float*)d_in[0];
    const float* item_emb = (const float*)d_in[1];
    const float* W0  = (const float*)d_in[2];
    const float* b0  = (const float*)d_in[3];
    const float* g0  = (const float*)d_in[4];
    const float* be0 = (const float*)d_in[5];
    const float* W1  = (const float*)d_in[6];
    const float* b1  = (const float*)d_in[7];
    const float* g1  = (const float*)d_in[8];
    const float* be1 = (const float*)d_in[9];
    const float* W2  = (const float*)d_in[10];
    const float* b2  = (const float*)d_in[11];
    const int* user_id  = (const int*)d_in[12];
    const int* pos_item = (const int*)d_in[13];
    const int* neg_item = (const int*)d_in[14];
    const int* edge     = (const int*)d_in[15];
    const int* src = edge;
    const int* dst = edge + N_EDGES;

    char* w = (char*)d_ws;
    auto alloc = [&](size_t bytes) -> char* {
        char* r = w;
        w += (bytes + 255) / 256 * 256;
        return r;
    };
    int*      cnt  = (int*)alloc((size_t)N_NODES * 4);
    int*      off  = (int*)alloc((size_t)(N_NODES + 1) * 4);
    int*      bcur = (int*)alloc((size_t)NBUCK * 4);
    uint2*    csr8 = (uint2*)alloc((size_t)N_EDGES * 8);
    float*    dis  = (float*)alloc((size_t)N_NODES * 4);
    int*      psum = (int*)alloc((size_t)SC_NB * 4);
    double*   part = (double*)alloc((size_t)STATS_NB * 256 * 8);
    float*    bn_a = (float*)alloc(128 * 4);
    float*    bn_b = (float*)alloc(128 * 4);
    ushort_t* hbuf = (ushort_t*)alloc((size_t)N_NODES * HID_DIM * 2);   // bf16 GEMM output
    float*    xbuf = (float*)alloc((size_t)N_NODES * HID_DIM * 4);      // fp32 agg output
    ushort_t* xbf  = (ushort_t*)alloc((size_t)N_NODES * HID_DIM * 2);   // bf16 normalized x

    // temp edge buffer for bucket pass reuses hbuf (38.4MB >= 19.2MB needed;
    // hbuf is first written by gemm0 AFTER the CSR build completes in-stream)
    uint2* temp = (uint2*)hbuf;

    float* out = (float*)d_out;
    float* X   = out + 1;   // node embeddings region (150000 x 64)

    const int EB = (N_EDGES + 255) / 256;
    const int NB = (N_NODES + 255) / 256;
    const int AGGB = (N_NODES + 3) / 4;
    const int GB = (N_NODES + 127) / 128;   // MFMA gemm blocks (128 rows each)

    // preprocessing: degree, dis, CSR via bucketed two-pass build
    zero_int_kernel<<<NB, 256, 0, stream>>>(cnt, N_NODES);
    count_kernel<<<EB, 256, 0, stream>>>(dst, cnt);
    dis_kernel<<<NB, 256, 0, stream>>>(cnt, dis);
    scan_part_kernel<<<SC_NB, 256, 0, stream>>>(cnt, psum);
    scan_mid_kernel<<<1, 256, 0, stream>>>(psum, off, SC_NB);
    scan_emit_kernel<<<SC_NB, 256, 0, stream>>>(cnt, psum, off);
    zero_int_kernel<<<(NBUCK + 255) / 256, 256, 0, stream>>>(bcur, NBUCK);
    bucket_part_kernel<<<P1_BLOCKS, 256, 0, stream>>>(src, dst, off, bcur, temp);
    bucket_fine_kernel<<<NBUCK, 256, 0, stream>>>(off, dis, temp, csr8);

    // layer 0: (150000x64 fp32) @ (64x128)
    gemm_kernel<float, 64, 128><<<GB, 256, 0, stream>>>(
        user_emb, item_emb, USER_NUM, W0, hbuf, N_NODES);
    agg_kernel<128><<<AGGB, 256, 0, stream>>>(hbuf, dis, off, csr8, b0, xbuf, N_NODES);
    stats1_kernel<<<STATS_NB, 128, 0, stream>>>(xbuf, part);
    stats2_kernel<<<128, 256, 0, stream>>>(part, g0, be0, bn_a, bn_b);
    bn_relu_l2_kernel<<<AGGB, 256, 0, stream>>>(xbuf, bn_a, bn_b, (uint_t*)xbf, N_NODES);

    // layer 1: (150000x128 bf16) @ (128x128)
    gemm_kernel<ushort_t, 128, 128><<<GB, 256, 0, stream>>>(
        xbf, xbf, N_NODES, W1, hbuf, N_NODES);
    agg_kernel<128><<<AGGB, 256, 0, stream>>>(hbuf, dis, off, csr8, b1, xbuf, N_NODES);
    stats1_kernel<<<STATS_NB, 128, 0, stream>>>(xbuf, part);
    stats2_kernel<<<128, 256, 0, stream>>>(part, g1, be1, bn_a, bn_b);
    bn_relu_l2_kernel<<<AGGB, 256, 0, stream>>>(xbuf, bn_a, bn_b, (uint_t*)xbf, N_NODES);

    // layer 2: (150000x128 bf16) @ (128x64)
    gemm_kernel<ushort_t, 128, 64><<<GB, 256, 0, stream>>>(
        xbf, xbf, N_NODES, W2, hbuf, N_NODES);
    agg_kernel<64><<<AGGB, 256, 0, stream>>>(hbuf, dis, off, csr8, b2, X, N_NODES);

    // loss
    zero_float_kernel<<<1, 1, 0, stream>>>(out);
    loss_kernel<<<(BATCH + 3) / 4, 256, 0, stream>>>(X, user_id, pos_item, neg_item, out);
}

// Round 15
// 955.117 us; speedup vs baseline: 1.2065x; 1.0130x over previous
//
#include <hip/hip_runtime.h>
#include <hip/hip_bf16.h>
#include <math.h>

#define USER_NUM 100000
#define ITEM_NUM 50000
#define N_NODES  150000
#define N_EDGES  2400000
#define OUT_DIM  64
#define HID_DIM  128
#define BATCH    4096
#define EPS_BN   1e-5f

typedef unsigned short ushort_t;
typedef unsigned int uint_t;
typedef unsigned long long ull_t;

typedef __attribute__((ext_vector_type(8))) __bf16 bf16x8;
typedef __attribute__((ext_vector_type(4))) float f32x4;

// fp32 -> bf16 (round-to-nearest-even), and back
__device__ __forceinline__ ushort_t f2bf(float f) {
    uint_t u = __float_as_uint(f);
    u += 0x7FFFu + ((u >> 16) & 1u);
    return (ushort_t)(u >> 16);
}
__device__ __forceinline__ float bf2f(ushort_t s) {
    return __uint_as_float((uint_t)s << 16);
}

// ---------------- preprocessing ----------------

__global__ __launch_bounds__(256) void zero_int_kernel(int* __restrict__ p, int n) {
    int i = blockIdx.x * 256 + threadIdx.x;
    if (i < n) p[i] = 0;
}

__global__ __launch_bounds__(256) void count_kernel(const int* __restrict__ dst, int* __restrict__ cnt) {
    int i = blockIdx.x * 256 + threadIdx.x;
    if (i < N_EDGES) atomicAdd(&cnt[dst[i]], 1);
}

__global__ __launch_bounds__(256) void dis_kernel(const int* __restrict__ cnt, float* __restrict__ dis) {
    int i = blockIdx.x * 256 + threadIdx.x;
    if (i < N_NODES) dis[i] = rsqrtf(1.0f + (float)cnt[i]);
}

// 3-pass scan: per-block sums -> scan of block sums -> emit offsets
#define SC_ELEM 1024
#define SC_NB   ((N_NODES + SC_ELEM - 1) / SC_ELEM)   // 147

__global__ __launch_bounds__(256) void scan_part_kernel(const int* __restrict__ cnt,
                                                        int* __restrict__ psum) {
    __shared__ int red[4];
    int tid = threadIdx.x;
    int base = blockIdx.x * SC_ELEM + tid * 4;
    int s = 0;
#pragma unroll
    for (int j = 0; j < 4; j++) { int i = base + j; if (i < N_NODES) s += cnt[i]; }
#pragma unroll
    for (int d = 1; d < 64; d <<= 1) s += __shfl_xor(s, d);
    if ((tid & 63) == 0) red[tid >> 6] = s;
    __syncthreads();
    if (tid == 0) psum[blockIdx.x] = red[0] + red[1] + red[2] + red[3];
}

__global__ __launch_bounds__(256) void scan_mid_kernel(int* __restrict__ psum,
                                                       int* __restrict__ off, int nb) {
    __shared__ int lds[256];
    int tid = threadIdx.x;
    int v = (tid < nb) ? psum[tid] : 0;
    lds[tid] = v;
    __syncthreads();
    for (int d = 1; d < 256; d <<= 1) {
        int t = (tid >= d) ? lds[tid - d] : 0;
        __syncthreads();
        lds[tid] += t;
        __syncthreads();
    }
    if (tid < nb) psum[tid] = lds[tid] - v;   // exclusive
    if (tid == 0) off[N_NODES] = lds[255];
}

__global__ __launch_bounds__(256) void scan_emit_kernel(const int* __restrict__ cnt,
                                                        const int* __restrict__ psum,
                                                        int* __restrict__ off) {
    __shared__ int lds[256];
    int tid = threadIdx.x;
    int base = blockIdx.x * SC_ELEM + tid * 4;
    int v[4]; int s = 0;
#pragma unroll
    for (int j = 0; j < 4; j++) {
        int i = base + j;
        v[j] = (i < N_NODES) ? cnt[i] : 0;
        s += v[j];
    }
    lds[tid] = s;
    __syncthreads();
    for (int d = 1; d < 256; d <<= 1) {
        int t = (tid >= d) ? lds[tid - d] : 0;
        __syncthreads();
        lds[tid] += t;
        __syncthreads();
    }
    int run = psum[blockIdx.x] + lds[tid] - s;
#pragma unroll
    for (int j = 0; j < 4; j++) {
        int i = base + j;
        if (i < N_NODES) off[i] = run;
        run += v[j];
    }
}

// ---------------- two-pass bucketed CSR build ----------------
// Bucket = dst>>9 (512 nodes, 293 buckets). Pass 1 groups edges by bucket
// into temp with per-block contiguous runs (lines written by one block,
// quickly -> write-combining works). Pass 2: one block per bucket does the
// fine scatter to exact CSR slots inside its contiguous ~65KB region.

#define BSH   9
#define NBUCK ((N_NODES + 511) / 512)     // 293
#define P1_BLOCKS 512

__global__ __launch_bounds__(256) void bucket_part_kernel(const int* __restrict__ src,
                                                          const int* __restrict__ dst,
                                                          const int* __restrict__ off,
                                                          int* __restrict__ bcur,
                                                          uint2* __restrict__ temp) {
    __shared__ int hist[NBUCK];
    __shared__ int base[NBUCK];
    const int per = (N_EDGES + P1_BLOCKS - 1) / P1_BLOCKS;   // 4688
    const int lo = blockIdx.x * per;
    int hi = lo + per; if (hi > N_EDGES) hi = N_EDGES;
    const int tid = threadIdx.x;
    for (int j = tid; j < NBUCK; j += 256) hist[j] = 0;
    __syncthreads();
    for (int i = lo + tid; i < hi; i += 256)
        atomicAdd(&hist[dst[i] >> BSH], 1);
    __syncthreads();
    for (int b = tid; b < NBUCK; b += 256) {
        int h = hist[b];
        if (h > 0) base[b] = off[b << BSH] + atomicAdd(&bcur[b], h);
    }
    __syncthreads();
    for (int i = lo + tid; i < hi; i += 256) {
        int d = dst[i];
        int p = atomicAdd(&base[d >> BSH], 1);
        temp[p] = make_uint2((uint_t)src[i], (uint_t)d);
    }
}

// CSR entry: .x = src node, .y = bit-pattern of edge weight dis[src]*dis[dst]
__global__ __launch_bounds__(256) void bucket_fine_kernel(const int* __restrict__ off,
                                                          const float* __restrict__ dis,
                                                          const uint2* __restrict__ temp,
                                                          uint2* __restrict__ csr8) {
    __shared__ int   offs[513];
    __shared__ int   cur[512];
    __shared__ float disd[512];
    const int b  = blockIdx.x;
    const int lo = b << BSH;
    int hi = lo + 512; if (hi > N_NODES) hi = N_NODES;
    const int nn = hi - lo;
    const int tid = threadIdx.x;
    for (int j = tid; j <= nn; j += 256) offs[j] = off[lo + j];
    for (int j = tid; j < nn; j += 256) { cur[j] = 0; disd[j] = dis[lo + j]; }
    __syncthreads();
    const int e0 = offs[0], e1 = offs[nn];
    for (int i = e0 + tid; i < e1; i += 256) {
        uint2 t = temp[i];
        int dl = (int)t.y - lo;
        int p = offs[dl] + atomicAdd(&cur[dl], 1);
        float wv = dis[t.x] * disd[dl];
        csr8[p] = make_uint2(t.x, __float_as_uint(wv));
    }
}

// ---------------- MFMA GEMM: out[M][DOUT] = x[M][DIN] @ W[DIN][DOUT], bf16 out --------------
// mfma_f32_16x16x32_bf16. 4 waves x 32 rows = 128 rows/block. W staged
// transposed in LDS as bf16 (+8 pad: 16B-aligned ds_read_b128 B-frags).
// A loaded directly from global (16B/lane). fp32 inputs converted on load.

__device__ __forceinline__ bf16x8 loadA(const ushort_t* p) {
    uint4 u = *(const uint4*)p;
    return __builtin_bit_cast(bf16x8, u);
}
__device__ __forceinline__ bf16x8 loadA(const float* p) {
    float4 f0 = *(const float4*)p;
    float4 f1 = *(const float4*)(p + 4);
    uint4 u;
    u.x = (uint_t)f2bf(f0.x) | ((uint_t)f2bf(f0.y) << 16);
    u.y = (uint_t)f2bf(f0.z) | ((uint_t)f2bf(f0.w) << 16);
    u.z = (uint_t)f2bf(f1.x) | ((uint_t)f2bf(f1.y) << 16);
    u.w = (uint_t)f2bf(f1.z) | ((uint_t)f2bf(f1.w) << 16);
    return __builtin_bit_cast(bf16x8, u);
}

template<typename XT, int DIN, int DOUT>
__global__ __launch_bounds__(256) void gemm_kernel(const XT* __restrict__ xlo,
                                                   const XT* __restrict__ xhi, int split,
                                                   const float* __restrict__ W,
                                                   ushort_t* __restrict__ out, int nrows) {
    constexpr int LDW = DIN + 8;                  // padded row (elems), 16B-aligned rows
    constexpr int NCT = DOUT / 16;                // column tiles
    __shared__ ushort_t wt[DOUT][LDW];            // W^T, bf16 bits

    const int tid = threadIdx.x;
    for (int idx = tid; idx < DIN * DOUT; idx += 256) {
        int k = idx / DOUT, n = idx % DOUT;
        wt[n][k] = f2bf(W[idx]);
    }
    __syncthreads();

    const int wave = tid >> 6, lane = tid & 63;
    const int lm = lane & 15, lk = lane >> 4;     // row-in-tile, k-group
    const int row0 = blockIdx.x * 128 + wave * 32;

    f32x4 acc[2][NCT];
#pragma unroll
    for (int rt = 0; rt < 2; rt++)
#pragma unroll
        for (int c = 0; c < NCT; c++) acc[rt][c] = (f32x4){0.f, 0.f, 0.f, 0.f};

    const XT* rp[2];
#pragma unroll
    for (int rt = 0; rt < 2; rt++) {
        int row = row0 + rt * 16 + lm;
        if (row > nrows - 1) row = nrows - 1;
        rp[rt] = (row < split) ? xlo + (size_t)row * DIN
                               : xhi + (size_t)(row - split) * DIN;
    }

#pragma unroll
    for (int ks = 0; ks < DIN / 32; ks++) {
        bf16x8 a0 = loadA(rp[0] + ks * 32 + lk * 8);
        bf16x8 a1 = loadA(rp[1] + ks * 32 + lk * 8);
#pragma unroll
        for (int c = 0; c < NCT; c++) {
            bf16x8 b = *(const bf16x8*)&wt[c * 16 + lm][ks * 32 + lk * 8];
            acc[0][c] = __builtin_amdgcn_mfma_f32_16x16x32_bf16(a0, b, acc[0][c], 0, 0, 0);
            acc[1][c] = __builtin_amdgcn_mfma_f32_16x16x32_bf16(a1, b, acc[1][c], 0, 0, 0);
        }
    }

    // C/D layout: col = lane&15, row = (lane>>4)*4 + r
#pragma unroll
    for (int rt = 0; rt < 2; rt++) {
#pragma unroll
        for (int r = 0; r < 4; r++) {
            int row = row0 + rt * 16 + lk * 4 + r;
            if (row < nrows) {
#pragma unroll
                for (int c = 0; c < NCT; c++)
                    __builtin_nontemporal_store(f2bf(acc[rt][c][r]),
                                                &out[(size_t)row * DOUT + c * 16 + lm]);
            }
        }
    }
}

// ---------------- edge aggregation (CSR gather over bf16 h), grid-stride ----------------
// out[i] = sum_e w_e*h[s_e] + h[i]*dis[i]^2 + bias   (fp32 accumulate/output)
// STATS: per-wave f32 column partials (sum, sumsq) -> part[gw][256]
// csr8 stream + out stream marked nontemporal (preserve L2 for the h gather).

#define AGG_BLOCKS 2048
#define NPART (AGG_BLOCKS * 4)     // 8192 wave partials

template<int DOUT, bool STATS>
__global__ __launch_bounds__(256) void agg_kernel(const ushort_t* __restrict__ h,
                                                  const float* __restrict__ dis,
                                                  const int* __restrict__ off,
                                                  const uint2* __restrict__ csr8,
                                                  const float* __restrict__ bias,
                                                  float* __restrict__ out,
                                                  float* __restrict__ part, int n) {
    const int wave = threadIdx.x >> 6;
    const int lane = threadIdx.x & 63;
    const int gw   = blockIdx.x * 4 + wave;       // global wave id
    const int NW   = AGG_BLOCKS * 4;

    float s1x = 0.f, s2x = 0.f, s1y = 0.f, s2y = 0.f;

    for (int node = gw; node < n; node += NW) {
        float di  = dis[node];
        int   beg = off[node], end = off[node + 1];
        if (DOUT == 128) {
            const uint_t* hp = (const uint_t*)h;   // 64 uints (128 bf16) per row
            float ax = 0.f, ay = 0.f;
            int e = beg;
            for (; e + 8 <= end; e += 8) {
                ull_t c[8];
#pragma unroll
                for (int j = 0; j < 8; j++)
                    c[j] = __builtin_nontemporal_load((const ull_t*)&csr8[e + j]);
                uint_t u[8];
#pragma unroll
                for (int j = 0; j < 8; j++)
                    u[j] = hp[(size_t)(uint_t)c[j] * 64 + lane];
#pragma unroll
                for (int j = 0; j < 8; j++) {
                    float wv = __uint_as_float((uint_t)(c[j] >> 32));
                    ax = fmaf(__uint_as_float(u[j] << 16), wv, ax);
                    ay = fmaf(__uint_as_float(u[j] & 0xFFFF0000u), wv, ay);
                }
            }
            for (; e < end; e++) {
                ull_t cv = __builtin_nontemporal_load((const ull_t*)&csr8[e]);
                float wv = __uint_as_float((uint_t)(cv >> 32));
                uint_t u = hp[(size_t)(uint_t)cv * 64 + lane];
                ax = fmaf(__uint_as_float(u << 16), wv, ax);
                ay = fmaf(__uint_as_float(u & 0xFFFF0000u), wv, ay);
            }
            uint_t us = hp[(size_t)node * 64 + lane];
            float2 bb = ((const float2*)bias)[lane];
            float dd = di * di;
            float ox = ax + __uint_as_float(us << 16) * dd + bb.x;
            float oy = ay + __uint_as_float(us & 0xFFFF0000u) * dd + bb.y;
            ull_t obits = __builtin_bit_cast(ull_t, make_float2(ox, oy));
            __builtin_nontemporal_store(obits, (ull_t*)&((float2*)out)[(size_t)node * 64 + lane]);
            if (STATS) {
                s1x += ox; s2x = fmaf(ox, ox, s2x);
                s1y += oy; s2y = fmaf(oy, oy, s2y);
            }
        } else {
            float ax = 0.f;
            int e = beg;
            for (; e + 8 <= end; e += 8) {
                ull_t c[8];
#pragma unroll
                for (int j = 0; j < 8; j++)
                    c[j] = __builtin_nontemporal_load((const ull_t*)&csr8[e + j]);
                float hv[8];
#pragma unroll
                for (int j = 0; j < 8; j++)
                    hv[j] = bf2f(h[(size_t)(uint_t)c[j] * 64 + lane]);
#pragma unroll
                for (int j = 0; j < 8; j++)
                    ax = fmaf(hv[j], __uint_as_float((uint_t)(c[j] >> 32)), ax);
            }
            for (; e < end; e++) {
                ull_t cv = __builtin_nontemporal_load((const ull_t*)&csr8[e]);
                ax = fmaf(bf2f(h[(size_t)(uint_t)cv * 64 + lane]),
                          __uint_as_float((uint_t)(cv >> 32)), ax);
            }
            float hs = bf2f(h[(size_t)node * 64 + lane]);
            float ox = ax + hs * di * di + bias[lane];
            __builtin_nontemporal_store(ox, &out[(size_t)node * 64 + lane]);
        }
    }

    if (STATS) {
        float* pp = part + (size_t)gw * 256;
        pp[lane * 2]           = s1x;
        pp[lane * 2 + 1]       = s1y;
        pp[128 + lane * 2]     = s2x;
        pp[128 + lane * 2 + 1] = s2y;
    }
}

// ---------------- BN stats final reduce: one block per column over wave partials ----------

__global__ __launch_bounds__(256) void stats2_kernel(const float* __restrict__ part,
                                                     const float* __restrict__ g,
                                                     const float* __restrict__ beta,
                                                     float* __restrict__ a_out,
                                                     float* __restrict__ b_out) {
    __shared__ double red1[4], red2[4];
    int col = blockIdx.x;       // 0..127
    int tid = threadIdx.x;
    double s1 = 0.0, s2 = 0.0;
    for (int p = tid; p < NPART; p += 256) {
        s1 += (double)part[(size_t)p * 256 + col];
        s2 += (double)part[(size_t)p * 256 + 128 + col];
    }
#pragma unroll
    for (int d = 32; d >= 1; d >>= 1) {
        s1 += __shfl_xor(s1, d);
        s2 += __shfl_xor(s2, d);
    }
    int wave = tid >> 6, lane = tid & 63;
    if (lane == 0) { red1[wave] = s1; red2[wave] = s2; }
    __syncthreads();
    if (tid == 0) {
        double t1 = red1[0] + red1[1] + red1[2] + red1[3];
        double t2 = red2[0] + red2[1] + red2[2] + red2[3];
        double mean = t1 / (double)N_NODES;
        double var  = t2 / (double)N_NODES - mean * mean;
        float inv = rsqrtf((float)var + EPS_BN);
        float aa  = g[col] * inv;
        a_out[col] = aa;
        b_out[col] = beta[col] - (float)mean * aa;
    }
}

// ---------------- fused BN-apply + ReLU + row L2-norm -> bf16 (wave per row) ----------------

__global__ __launch_bounds__(256) void bn_relu_l2_kernel(const float* __restrict__ in,
                                                         const float* __restrict__ a,
                                                         const float* __restrict__ b,
                                                         uint_t* __restrict__ outp, int n) {
    int wave = threadIdx.x >> 6;
    int lane = threadIdx.x & 63;
    int row  = blockIdx.x * 4 + wave;
    if (row >= n) return;
    float2 v  = *(const float2*)(in + (size_t)row * 128 + lane * 2);
    float2 aa = *(const float2*)(a + lane * 2);
    float2 bb = *(const float2*)(b + lane * 2);
    float y0 = fmaxf(fmaf(v.x, aa.x, bb.x), 0.f);
    float y1 = fmaxf(fmaf(v.y, aa.y, bb.y), 0.f);
    float ss = y0 * y0 + y1 * y1;
#pragma unroll
    for (int d = 32; d >= 1; d >>= 1) ss += __shfl_xor(ss, d);
    float nn  = sqrtf(ss);
    float inv = 1.f / fmaxf(nn, 1e-12f);
    uint_t pk = (uint_t)f2bf(y0 * inv) | ((uint_t)f2bf(y1 * inv) << 16);
    outp[(size_t)row * 64 + lane] = pk;
}

// ---------------- loss ----------------

__global__ void zero_float_kernel(float* p) { *p = 0.f; }

__global__ __launch_bounds__(256) void loss_kernel(const float* __restrict__ X,
                                                   const int* __restrict__ uid,
                                                   const int* __restrict__ pid,
                                                   const int* __restrict__ nid,
                                                   float* __restrict__ out0) {
    int wave = threadIdx.x >> 6;
    int lane = threadIdx.x & 63;
    int b = blockIdx.x * 4 + wave;
    if (b >= BATCH) return;
    const float* u = X + (size_t)uid[b] * OUT_DIM;
    const float* p = X + (size_t)(USER_NUM + pid[b]) * OUT_DIM;
    const float* q = X + (size_t)(USER_NUM + nid[b]) * OUT_DIM;
    float uv = u[lane];
    float ps = uv * p[lane];
    float ns = uv * q[lane];
#pragma unroll
    for (int d = 32; d >= 1; d >>= 1) {
        ps += __shfl_xor(ps, d);
        ns += __shfl_xor(ns, d);
    }
    if (lane == 0) {
        float t  = ns - ps;                                   // -(pos - neg)
        float sp = fmaxf(t, 0.f) + log1pf(expf(-fabsf(t)));   // softplus(t)
        atomicAdd(out0, sp * (1.0f / BATCH));
    }
}

// ---------------- launch ----------------

extern "C" void kernel_launch(void* const* d_in, const int* in_sizes, int n_in,
                              void* d_out, int out_size, void* d_ws, size_t ws_size,
                              hipStream_t stream) {
    const float* user_emb = (const float*)d_in[0];
    const float* item_emb = (const float*)d_in[1];
    const float* W0  = (const float*)d_in[2];
    const float* b0  = (const float*)d_in[3];
    const float* g0  = (const float*)d_in[4];
    const float* be0 = (const float*)d_in[5];
    const float* W1  = (const float*)d_in[6];
    const float* b1  = (const float*)d_in[7];
    const float* g1  = (const float*)d_in[8];
    const float* be1 = (const float*)d_in[9];
    const float* W2  = (const float*)d_in[10];
    const float* b2  = (const float*)d_in[11];
    const int* user_id  = (const int*)d_in[12];
    const int* pos_item = (const int*)d_in[13];
    const int* neg_item = (const int*)d_in[14];
    const int* edge     = (const int*)d_in[15];
    const int* src = edge;
    const int* dst = edge + N_EDGES;

    char* w = (char*)d_ws;
    auto alloc = [&](size_t bytes) -> char* {
        char* r = w;
        w += (bytes + 255) / 256 * 256;
        return r;
    };
    int*      cnt  = (int*)alloc((size_t)N_NODES * 4);
    int*      off  = (int*)alloc((size_t)(N_NODES + 1) * 4);
    int*      bcur = (int*)alloc((size_t)NBUCK * 4);
    uint2*    csr8 = (uint2*)alloc((size_t)N_EDGES * 8);
    float*    dis  = (float*)alloc((size_t)N_NODES * 4);
    int*      psum = (int*)alloc((size_t)SC_NB * 4);
    float*    part = (float*)alloc((size_t)NPART * 256 * 4);
    float*    bn_a = (float*)alloc(128 * 4);
    float*    bn_b = (float*)alloc(128 * 4);
    ushort_t* hbuf = (ushort_t*)alloc((size_t)N_NODES * HID_DIM * 2);   // bf16 GEMM output
    float*    xbuf = (float*)alloc((size_t)N_NODES * HID_DIM * 4);      // fp32 agg output
    ushort_t* xbf  = (ushort_t*)alloc((size_t)N_NODES * HID_DIM * 2);   // bf16 normalized x

    // temp edge buffer for bucket pass reuses hbuf (38.4MB >= 19.2MB needed;
    // hbuf is first written by gemm0 AFTER the CSR build completes in-stream)
    uint2* temp = (uint2*)hbuf;

    float* out = (float*)d_out;
    float* X   = out + 1;   // node embeddings region (150000 x 64)

    const int EB = (N_EDGES + 255) / 256;
    const int NB = (N_NODES + 255) / 256;
    const int BNB = (N_NODES + 3) / 4;
    const int GB = (N_NODES + 127) / 128;   // MFMA gemm blocks (128 rows each)

    // preprocessing: degree, dis, CSR via bucketed two-pass build
    zero_int_kernel<<<NB, 256, 0, stream>>>(cnt, N_NODES);
    count_kernel<<<EB, 256, 0, stream>>>(dst, cnt);
    dis_kernel<<<NB, 256, 0, stream>>>(cnt, dis);
    scan_part_kernel<<<SC_NB, 256, 0, stream>>>(cnt, psum);
    scan_mid_kernel<<<1, 256, 0, stream>>>(psum, off, SC_NB);
    scan_emit_kernel<<<SC_NB, 256, 0, stream>>>(cnt, psum, off);
    zero_int_kernel<<<(NBUCK + 255) / 256, 256, 0, stream>>>(bcur, NBUCK);
    bucket_part_kernel<<<P1_BLOCKS, 256, 0, stream>>>(src, dst, off, bcur, temp);
    bucket_fine_kernel<<<NBUCK, 256, 0, stream>>>(off, dis, temp, csr8);

    // layer 0: (150000x64 fp32) @ (64x128)
    gemm_kernel<float, 64, 128><<<GB, 256, 0, stream>>>(
        user_emb, item_emb, USER_NUM, W0, hbuf, N_NODES);
    agg_kernel<128, true><<<AGG_BLOCKS, 256, 0, stream>>>(
        hbuf, dis, off, csr8, b0, xbuf, part, N_NODES);
    stats2_kernel<<<128, 256, 0, stream>>>(part, g0, be0, bn_a, bn_b);
    bn_relu_l2_kernel<<<BNB, 256, 0, stream>>>(xbuf, bn_a, bn_b, (uint_t*)xbf, N_NODES);

    // layer 1: (150000x128 bf16) @ (128x128)
    gemm_kernel<ushort_t, 128, 128><<<GB, 256, 0, stream>>>(
        xbf, xbf, N_NODES, W1, hbuf, N_NODES);
    agg_kernel<128, true><<<AGG_BLOCKS, 256, 0, stream>>>(
        hbuf, dis, off, csr8, b1, xbuf, part, N_NODES);
    stats2_kernel<<<128, 256, 0, stream>>>(part, g1, be1, bn_a, bn_b);
    bn_relu_l2_kernel<<<BNB, 256, 0, stream>>>(xbuf, bn_a, bn_b, (uint_t*)xbf, N_NODES);

    // layer 2: (150000x128 bf16) @ (128x64)
    gemm_kernel<ushort_t, 128, 64><<<GB, 256, 0, stream>>>(
        xbf, xbf, N_NODES, W2, hbuf, N_NODES);
    agg_kernel<64, false><<<AGG_BLOCKS, 256, 0, stream>>>(
        hbuf, dis, off, csr8, b2, X, part, N_NODES);

    // loss
    zero_float_kernel<<<1, 1, 0, stream>>>(out);
    loss_kernel<<<(BATCH + 3) / 4, 256, 0, stream>>>(X, user_id, pos_item, neg_item, out);
}